// Round 18
// baseline (298.196 us; speedup 1.0000x reference)
//
#include <hip/hip_runtime.h>
#include <hip/hip_bf16.h>

typedef __hip_bfloat16 bf16;
typedef float f32x4 __attribute__((ext_vector_type(4)));
typedef short bf16x8s __attribute__((ext_vector_type(8)));
typedef unsigned short u16x8 __attribute__((ext_vector_type(8)));

constexpr int N_HE = 50000;
constexpr int M_PAD = 50048;           // 391 * 128
constexpr int E_EDGES = 1200000;
constexpr int IN_F = 200;
constexpr int KP_HE = 224;             // 200 padded to x32
constexpr int HE_DIM = 512;
constexpr int E_DIM = 128;
constexpr int Q_DIM = 64;
constexpr float SL2E = 0.125f * 1.44269504088896f; // SCALE * log2(e), folded into W_R/bR
constexpr int N_NODES = 1489;
constexpr int R_STRIDE = 216;          // valid R cols: 3 x 72 (64 r + 1 c + 7 pad)
constexpr int R_LD = 224;              // R row stride (floats): 896 B, 64B-aligned rows
constexpr int T_STRIDE = 192;          // 3 x 64
constexpr int LDSD = 40;               // LDS row stride (bf16): 80B
constexpr int NBIN = 98;               // ceil(50000/512) bins per group
constexpr int BIN_SHIFT = 9;           // 512 hyperedges per bin
constexpr int ECHUNK = 4096;           // edges per scatter block
constexpr int NCHUNK = (E_EDGES + ECHUNK - 1) / ECHUNK; // 293
constexpr int BINCAP = 13056;          // mean 12288 + 7 sigma, clamp-guarded
constexpr int SCAT_BLKS = 3 * NCHUNK;  // 879
constexpr int PREP_BLKS = 256 + 193 + 128 + N_NODES; // 2066
constexpr int MB = M_PAD / 128;        // 391

struct EdgeIdx { const int* p[3]; };

__device__ __forceinline__ void split2(float v, bf16& h, bf16& l)
{
    bf16 hb = __float2bfloat16(v);
    h = hb;
    l = __float2bfloat16(v - __bfloat162float(hb));
}
__device__ __forceinline__ void split2u(float v, unsigned short& h, unsigned short& l)
{
    bf16 hb = __float2bfloat16(v);
    bf16 lb = __float2bfloat16(v - __bfloat162float(hb));
    h = *reinterpret_cast<unsigned short*>(&hb);
    l = *reinterpret_cast<unsigned short*>(&lb);
}
__device__ __forceinline__ unsigned short bf16bits(float v)
{
    bf16 b = __float2bfloat16(v);
    return *reinterpret_cast<unsigned short*>(&b);
}
__device__ __forceinline__ float exp2_fast(float x)
{
    float r;
    asm("v_exp_f32 %0, %1" : "=v"(r) : "v"(x));
    return r;
}
// 16-lane (DPP-row) sum reduction, pure VALU. All lanes get the row sum.
__device__ __forceinline__ float red16(float x)
{
    x += __int_as_float(__builtin_amdgcn_update_dpp(0, __float_as_int(x), 0xB1, 0xF, 0xF, true));
    x += __int_as_float(__builtin_amdgcn_update_dpp(0, __float_as_int(x), 0x4E, 0xF, 0xF, true));
    x += __int_as_float(__builtin_amdgcn_update_dpp(0, __float_as_int(x), 0x141, 0xF, 0xF, true));
    x += __int_as_float(__builtin_amdgcn_update_dpp(0, __float_as_int(x), 0x140, 0xF, 0xF, true));
    return x;
}
// XCD-locality swizzle: all `nby` blocks sharing one A-tile get equal q mod 8 -> same XCD.
__device__ __forceinline__ void xcd_swizzle(int q, int total, int nby, int& bx, int& by)
{
    int grpsz = 8 * nby;
    int full = (total / grpsz) * grpsz;
    if (q < full) {
        bx = (q / grpsz) * 8 + (q & 7);
        by = (q >> 3) % nby;
    } else {
        int t = q - full;
        bx = full / nby + t / nby;
        by = t % nby;
    }
}

// ================= fused: bin_scatter (879 blocks) + prep (2066 blocks) =================
struct PrepArgs {
    const float *w1w, *w1b, *w2w, *w2b;
    const float *w6[3], *b6[3];
    bf16 *WRt_hi, *WRt_lo;
    float *bR;
    const float *w7[3], *b7[3];
    const float *mlp1w, *mlp1b;
    bf16 *Wct_hi, *Wct_lo;
    float *b_comp;
    const float *mlp2w;
    bf16 *Wm2t_hi, *Wm2t_lo;
    const float *feat[3], *w5[3], *b5[3];
    float *q_t;
};

__global__ __launch_bounds__(256) void scatter_prep_fused_kernel(
    EdgeIdx S, EdgeIdx D, int* __restrict__ bincursor, unsigned* __restrict__ binbuf,
    PrepArgs P)
{
    __shared__ unsigned stage[ECHUNK];
    __shared__ int hist4[4][NBIN];
    __shared__ int hist[NBIN], off[NBIN], cur[NBIN], gbase[NBIN];
    int bid = blockIdx.x, tid = threadIdx.x;
    if (bid < SCAT_BLKS) {
        // ---------------- bin_scatter ----------------
        int g = bid / NCHUNK, chunk = bid - g * NCHUNK;
        const int* src = S.p[g];
        const int* dst = D.p[g];
        int lane = tid & 63, w = tid >> 6;
        for (int b = tid; b < 4 * NBIN; b += 256) (&hist4[0][0])[b] = 0;
        __syncthreads();
        int base = chunk * ECHUNK;
        int s[ECHUNK / 256], d[ECHUNK / 256];
#pragma unroll
        for (int k = 0; k < ECHUNK / 256; ++k) {
            int i = base + k * 256 + tid;
            if (i < E_EDGES) {
                s[k] = src[i];
                d[k] = dst[i];
                atomicAdd(&hist4[w][s[k] >> BIN_SHIFT], 1);
            } else s[k] = -1;
        }
        __syncthreads();
        if (w == 0) {
            int i1 = 64 + lane;
            int v0 = 0, v1 = 0;
            if (lane < NBIN) v0 = hist4[0][lane] + hist4[1][lane] + hist4[2][lane] + hist4[3][lane];
            if (i1 < NBIN) v1 = hist4[0][i1] + hist4[1][i1] + hist4[2][i1] + hist4[3][i1];
            int x0 = v0, x1 = v1;
#pragma unroll
            for (int o = 1; o < 64; o <<= 1) {
                int t0 = __shfl_up(x0, o, 64);
                int t1 = __shfl_up(x1, o, 64);
                if (lane >= o) { x0 += t0; x1 += t1; }
            }
            int tot0 = __shfl(x0, 63, 64);
            if (lane < NBIN) { hist[lane] = v0; off[lane] = x0 - v0; cur[lane] = x0 - v0; }
            if (i1 < NBIN) { hist[i1] = v1; off[i1] = tot0 + x1 - v1; cur[i1] = tot0 + x1 - v1; }
        }
        __syncthreads();
        if (tid < NBIN) gbase[tid] = hist[tid] ? atomicAdd(&bincursor[g * NBIN + tid], hist[tid]) : 0;
        __syncthreads();
#pragma unroll
        for (int k = 0; k < ECHUNK / 256; ++k) {
            if (s[k] >= 0) {
                int bin = s[k] >> BIN_SHIFT;
                int pos = atomicAdd(&cur[bin], 1);
                stage[pos] = ((unsigned)(s[k] & 511) << 10) | (unsigned)d[k];
            }
        }
        __syncthreads();
        size_t gslot = (size_t)g * NBIN * BINCAP;
        for (int b = w; b < NBIN; b += 4) {
            int len = hist[b];
            if (!len) continue;
            int gb = gbase[b];
            int avail = BINCAP - gb;
            if (avail <= 0) continue;
            if (len > avail) len = avail;
            int lo = off[b];
            size_t obase = gslot + (size_t)b * BINCAP + gb;
            for (int j = lane; j < len; j += 64)
                binbuf[obase + j] = stage[lo + j];
        }
        return;
    }
    // ---------------- prep (reuses `stage` LDS as float scratch) ----------------
    float* sh = (float*)stage;
    int pb = bid - SCAT_BLKS;
    if (pb < 256) {
        // W_R column c: bkv_c -> M2 = w2w@bkv_c -> W_R[:,c] = w1w@M2 (*SL2E); bR_c
        int c = pb;
        const bf16 z = __float2bfloat16(0.f);
        if (c >= R_STRIDE) {
            if (tid < KP_HE) { P.WRt_hi[c * KP_HE + tid] = z; P.WRt_lo[c * KP_HE + tid] = z; }
            return;
        }
        float* bkv = sh;          // [128]
        float* M2 = sh + 128;     // [512]
        float* psum = sh + 640;   // [32]
        int g = c / 72, j = c - g * 72;
        if (tid < 128) {
            float v = 0.f;
            if (j < 64) v = P.w6[g][j * E_DIM + tid];
            else if (j == 64) v = P.b6[g][tid];
            bkv[tid] = v;
        }
        __syncthreads();
        for (int h = tid; h < HE_DIM; h += 256) {
            const float* w2row = P.w2w + (size_t)h * E_DIM;
            float s = 0.f;
#pragma unroll 4
            for (int k = 0; k < 128; ++k) s = fmaf(w2row[k], bkv[k], s);
            M2[h] = s;
        }
        __syncthreads();
        if (tid < IN_F) {
            const float* w1row = P.w1w + (size_t)tid * HE_DIM;
            float s = 0.f;
#pragma unroll 4
            for (int h = 0; h < HE_DIM; ++h) s = fmaf(w1row[h], M2[h], s);
            bf16 hh, ll; split2(s * SL2E, hh, ll);
            P.WRt_hi[c * KP_HE + tid] = hh;
            P.WRt_lo[c * KP_HE + tid] = ll;
        } else if (tid < KP_HE) {
            P.WRt_hi[c * KP_HE + tid] = z;
            P.WRt_lo[c * KP_HE + tid] = z;
        } else {
            int l = tid - 224; // 0..31
            float s = 0.f;
#pragma unroll 4
            for (int h = l * 16; h < l * 16 + 16; ++h) s = fmaf(P.w1b[h], M2[h], s);
#pragma unroll
            for (int k = l * 4; k < l * 4 + 4; ++k) s = fmaf(P.w2b[k], bkv[k], s);
            psum[l] = s;
        }
        __syncthreads();
        if (tid == 224) {
            float s = 0.f;
#pragma unroll
            for (int l = 0; l < 32; ++l) s += psum[l];
            P.bR[c] = s * SL2E;
        }
    } else if (pb < 449) {
        // Wct^T hi/lo [256][192]; row 192 -> b_comp
        int row = pb - 256;
        int n = tid;
        if (row < 192) {
            int g = row >> 6, i = row & 63;
            const float* w7 = P.w7[g];
            float s = 0.f;
#pragma unroll 4
            for (int k = 0; k < 128; ++k)
                s = fmaf(w7[i * 128 + k], P.mlp1w[(size_t)(g * 128 + k) * 256 + n], s);
            bf16 h, l; split2(s, h, l);
            P.Wct_hi[n * T_STRIDE + row] = h;
            P.Wct_lo[n * T_STRIDE + row] = l;
        } else {
            float s = P.mlp1b[n];
            for (int g = 0; g < 3; ++g)
#pragma unroll 4
                for (int k = 0; k < 128; ++k)
                    s = fmaf(P.b7[g][k], P.mlp1w[(size_t)(g * 128 + k) * 256 + n], s);
            P.b_comp[n] = s;
        }
    } else if (pb < 577) {
        // mlp2w^T hi/lo [128][256]
        int n = pb - 449;
        int k = tid;
        float v = P.mlp2w[(size_t)k * 128 + n];
        bf16 h, l; split2(v, h, l);
        P.Wm2t_hi[n * 256 + k] = h;
        P.Wm2t_lo[n * 256 + k] = l;
    } else {
        // node q projection: one block per node row
        int b = pb - 577; // 0..1488
        int g = (b < 167) ? 0 : (b < 1048 ? 1 : 2);
        int row = b - (g == 0 ? 0 : (g == 1 ? 167 : 1048));
        int Dt = (g == 0) ? 167 : (g == 1 ? 881 : 441);
        const float* feat = P.feat[g] + (size_t)row * Dt;
        const float* w5 = P.w5[g];
        int col = tid & 63, ks = tid >> 6;
        float s = 0.f;
#pragma unroll 4
        for (int k = ks; k < Dt; k += 4)
            s = fmaf(feat[k], w5[k * Q_DIM + col], s);
        sh[ks * 64 + col] = s;
        __syncthreads();
        if (ks == 0)
            P.q_t[(size_t)b * Q_DIM + col] =
                sh[col] + sh[64 + col] + sh[128 + col] + sh[192 + col] + P.b5[g][col];
    }
}

// ---------------- f32-A split-3-pass MFMA GEMM body: A staged in LDS, B direct from L2 ----------------
__device__ __forceinline__ void gemm_f32A_body(
    char* smem, int bx, int by, int tid,
    const float* __restrict__ A, int lda, int Kp, int Mvalid,
    const bf16* __restrict__ Bthg, const bf16* __restrict__ Btlg,
    const float* __restrict__ bias,
    float* __restrict__ C, int M, int N, int ldc)
{
    bf16* Ah = (bf16*)smem;
    bf16* Al = Ah + 128 * LDSD;
    const int bm = bx * 128, bn = by * 64;
    const int lane = tid & 63, w = tid >> 6;
    const int kgrp = lane >> 4, lr = lane & 15;
    const int arow = tid >> 1, ahalf = (tid & 1) * 16;
    f32x4 acc[2][4] = {};

    float va[16];
    const int arowg = bm + arow;

    // prologue A load (k0 = 0)
    {
        int kb = ahalf;
        if (arowg < Mvalid && kb + 16 <= lda) {
            const float* ap = A + (size_t)arowg * lda + kb;
            *(float4*)&va[0]  = *(const float4*)ap;
            *(float4*)&va[4]  = *(const float4*)(ap + 4);
            *(float4*)&va[8]  = *(const float4*)(ap + 8);
            *(float4*)&va[12] = *(const float4*)(ap + 12);
        } else {
#pragma unroll
            for (int j = 0; j < 16; ++j) {
                int k = kb + j;
                va[j] = (arowg < Mvalid && k < lda) ? A[(size_t)arowg * lda + k] : 0.f;
            }
        }
    }

    for (int k0 = 0; k0 < Kp; k0 += 32) {
        // stage current A regs -> LDS (split in flight)
        {
            u16x8 H0, H1, L0, L1;
#pragma unroll
            for (int j = 0; j < 8; ++j) {
                unsigned short h, l;
                split2u(va[j], h, l);       H0[j] = h; L0[j] = l;
                split2u(va[8 + j], h, l);   H1[j] = h; L1[j] = l;
            }
            *(u16x8*)&Ah[arow * LDSD + ahalf] = H0;
            *(u16x8*)&Ah[arow * LDSD + ahalf + 8] = H1;
            *(u16x8*)&Al[arow * LDSD + ahalf] = L0;
            *(u16x8*)&Al[arow * LDSD + ahalf + 8] = L1;
        }
        // prefetch next A K-step (hidden under barrier + MFMA)
        if (k0 + 32 < Kp) {
            int kb = k0 + 32 + ahalf;
            if (arowg < Mvalid && kb + 16 <= lda) {
                const float* ap = A + (size_t)arowg * lda + kb;
                *(float4*)&va[0]  = *(const float4*)ap;
                *(float4*)&va[4]  = *(const float4*)(ap + 4);
                *(float4*)&va[8]  = *(const float4*)(ap + 8);
                *(float4*)&va[12] = *(const float4*)(ap + 12);
            } else {
#pragma unroll
                for (int j = 0; j < 16; ++j) {
                    int k = kb + j;
                    va[j] = (arowg < Mvalid && k < lda) ? A[(size_t)arowg * lda + k] : 0.f;
                }
            }
        }
        // B fragments direct from L2 (WRt is small & hot; no LDS staging)
        bf16x8s bfh[4], bfl[4];
#pragma unroll
        for (int ni = 0; ni < 4; ++ni) {
            const size_t boff = (size_t)(bn + ni * 16 + lr) * Kp + k0 + kgrp * 8;
            bfh[ni] = *(const bf16x8s*)(Bthg + boff);
            bfl[ni] = *(const bf16x8s*)(Btlg + boff);
        }
        __syncthreads();
        bf16x8s afh[2], afl[2];
#pragma unroll
        for (int mi = 0; mi < 2; ++mi) {
            int r = w * 32 + mi * 16 + lr;
            afh[mi] = *(const bf16x8s*)&Ah[r * LDSD + kgrp * 8];
            afl[mi] = *(const bf16x8s*)&Al[r * LDSD + kgrp * 8];
        }
#pragma unroll
        for (int mi = 0; mi < 2; ++mi)
#pragma unroll
            for (int ni = 0; ni < 4; ++ni) {
                acc[mi][ni] = __builtin_amdgcn_mfma_f32_16x16x32_bf16(afh[mi], bfh[ni], acc[mi][ni], 0, 0, 0);
                acc[mi][ni] = __builtin_amdgcn_mfma_f32_16x16x32_bf16(afl[mi], bfh[ni], acc[mi][ni], 0, 0, 0);
                acc[mi][ni] = __builtin_amdgcn_mfma_f32_16x16x32_bf16(afh[mi], bfl[ni], acc[mi][ni], 0, 0, 0);
            }
        __syncthreads();
    }

    // LDS-transpose epilogue: full-line float4 stores (per-wave 4KB region)
    float* ep = (float*)(smem + w * 4096);
    float bv[4];
#pragma unroll
    for (int ni = 0; ni < 4; ++ni) {
        int col = bn + ni * 16 + lr;
        bv[ni] = (col < N) ? bias[col] : 0.f;
    }
    __syncthreads();
#pragma unroll
    for (int mi = 0; mi < 2; ++mi) {
#pragma unroll
        for (int ni = 0; ni < 4; ++ni)
#pragma unroll
            for (int r = 0; r < 4; ++r)
                ep[(kgrp * 4 + r) * 64 + ni * 16 + lr] = acc[mi][ni][r] + bv[ni];
#pragma unroll
        for (int s = 0; s < 4; ++s) {
            int row = s * 4 + (lane >> 4);
            int colv = lane & 15;
            int row_g = bm + w * 32 + mi * 16 + row;
            int col_g = bn + colv * 4;
            if (row_g < M && col_g + 4 <= N) {
                float4 v = *(const float4*)&ep[row * 64 + colv * 4];
                *(float4*)&C[(size_t)row_g * ldc + col_g] = v;
            }
        }
        if (mi == 0) __syncthreads();
    }
}

// ---------------- fused: R-gemm FIRST (1564 blocks, XCD-swizzled) + bin_csr (294 blocks) ----------------
__global__ __launch_bounds__(256) void csr_gemm_fused_kernel(
    const unsigned* __restrict__ binbuf, const int* __restrict__ bincursor,
    int2* __restrict__ rows2_all, int* __restrict__ ebuf,
    const float* __restrict__ he_feat,
    const bf16* __restrict__ WRt_hi, const bf16* __restrict__ WRt_lo,
    const float* __restrict__ bR, float* __restrict__ R)
{
    __shared__ __attribute__((aligned(16))) char smem[20480];
    int bid = blockIdx.x, tid = threadIdx.x;
    if (bid < MB * 4) {
        int bx, by;
        xcd_swizzle(bid, MB * 4, 4, bx, by);
        gemm_f32A_body(smem, bx, by, tid,
                       he_feat, IN_F, KP_HE, N_HE, WRt_hi, WRt_lo, bR,
                       R, N_HE, R_STRIDE, R_LD);
    } else {
        int cid = bid - MB * 4;
        int* hist = (int*)smem;
        int* cur = hist + 512;
        int* cs = cur + 512;
        int g = cid / NBIN, b = cid - g * NBIN;
        int cnt = min(bincursor[g * NBIN + b], BINCAP);
        size_t sbase = ((size_t)g * NBIN + b) * BINCAP;
        int h0 = b << BIN_SHIFT;
        int hN = min(512, N_HE - h0);
        int ebase_rel = b * BINCAP;
        int2* rows2 = rows2_all + g * N_HE;
        int lane = tid & 63, w = tid >> 6;
        hist[tid] = 0; hist[tid + 256] = 0;
        __syncthreads();
        for (int i = tid; i < cnt; i += 256)
            atomicAdd(&hist[binbuf[sbase + i] >> 10], 1);
        __syncthreads();
#pragma unroll
        for (int c2 = 0; c2 < 2; ++c2) {
            int c = w * 2 + c2, idx = c * 64 + lane;
            int v = hist[idx], x = v;
#pragma unroll
            for (int o = 1; o < 64; o <<= 1) {
                int t = __shfl_up(x, o, 64);
                if (lane >= o) x += t;
            }
            cur[idx] = x - v;
            if (lane == 63) cs[c] = x;
        }
        __syncthreads();
        if (tid == 0) {
            int run = 0;
#pragma unroll
            for (int c = 0; c < 8; ++c) { int t = cs[c]; cs[c] = run; run += t; }
        }
        __syncthreads();
#pragma unroll
        for (int c2 = 0; c2 < 2; ++c2) {
            int c = w * 2 + c2, idx = c * 64 + lane;
            int e = cur[idx] + cs[c];
            cur[idx] = e;
            if (idx < hN) rows2[h0 + idx] = make_int2(ebase_rel + e, ebase_rel + e + hist[idx]);
        }
        __syncthreads();
        for (int i = tid; i < cnt; i += 256) {
            unsigned p = binbuf[sbase + i];
            int pos = atomicAdd(&cur[p >> 10], 1);
            ebuf[sbase + pos] = (int)((p & 1023u) << 8); // byte offset into q_t rows (256 B/row)
        }
    }
}

// ---------------- bf16-A 2-pass MFMA GEMM: A in LDS, B direct from L2, LDS-transpose epilogue ----------------
template <bool OUT_BF16, bool MASK_ROW>
__global__ __launch_bounds__(256) void mfma_gemm_bf16A_kernel(
    int nby,
    const bf16* __restrict__ A, int lda, int Kp,
    const bf16* __restrict__ Bthg, const bf16* __restrict__ Btlg,
    const float* __restrict__ bias,
    float* __restrict__ Cf, bf16* __restrict__ Cb,
    int M, int N, int ldc)
{
    __shared__ __attribute__((aligned(16))) char smemB[16384];
    bf16* Ah = (bf16*)smemB;
    const int tid = threadIdx.x;
    int bx, by;
    xcd_swizzle(blockIdx.x, gridDim.x, nby, bx, by);
    const int bm = bx * 128, bn = by * 64;
    const int lane = tid & 63, w = tid >> 6;
    const int kgrp = lane >> 4, lr = lane & 15;
    const int arow = tid >> 1, ahalf = (tid & 1) * 16;
    f32x4 acc[2][4] = {};

    uint4 ra0, ra1;
    {
        const bf16* ap = A + (size_t)(bm + arow) * lda + ahalf;
        ra0 = *(const uint4*)ap;
        ra1 = *(const uint4*)(ap + 8);
    }

    for (int k0 = 0; k0 < Kp; k0 += 32) {
        *(uint4*)&Ah[arow * LDSD + ahalf] = ra0;
        *(uint4*)&Ah[arow * LDSD + ahalf + 8] = ra1;
        if (k0 + 32 < Kp) {
            const bf16* ap = A + (size_t)(bm + arow) * lda + k0 + 32 + ahalf;
            ra0 = *(const uint4*)ap;
            ra1 = *(const uint4*)(ap + 8);
        }
        bf16x8s bfh[4], bfl[4];
#pragma unroll
        for (int ni = 0; ni < 4; ++ni) {
            const size_t boff = (size_t)(bn + ni * 16 + lr) * Kp + k0 + kgrp * 8;
            bfh[ni] = *(const bf16x8s*)(Bthg + boff);
            bfl[ni] = *(const bf16x8s*)(Btlg + boff);
        }
        __syncthreads();
        bf16x8s afh[2];
#pragma unroll
        for (int mi = 0; mi < 2; ++mi) {
            int r = w * 32 + mi * 16 + lr;
            afh[mi] = *(const bf16x8s*)&Ah[r * LDSD + kgrp * 8];
        }
#pragma unroll
        for (int mi = 0; mi < 2; ++mi)
#pragma unroll
            for (int ni = 0; ni < 4; ++ni) {
                acc[mi][ni] = __builtin_amdgcn_mfma_f32_16x16x32_bf16(afh[mi], bfh[ni], acc[mi][ni], 0, 0, 0);
                acc[mi][ni] = __builtin_amdgcn_mfma_f32_16x16x32_bf16(afh[mi], bfl[ni], acc[mi][ni], 0, 0, 0);
            }
        __syncthreads();
    }

    // LDS-transpose epilogue (per-wave 4KB region)
    float bv[4];
#pragma unroll
    for (int ni = 0; ni < 4; ++ni) {
        int col = bn + ni * 16 + lr;
        bv[ni] = (col < N) ? bias[col] : 0.f;
    }
    __syncthreads();
    if (OUT_BF16) {
        unsigned short* ep = (unsigned short*)(smemB + w * 4096);
#pragma unroll
        for (int mi = 0; mi < 2; ++mi) {
#pragma unroll
            for (int ni = 0; ni < 4; ++ni)
#pragma unroll
                for (int r = 0; r < 4; ++r)
                    ep[(kgrp * 4 + r) * 64 + ni * 16 + lr] = bf16bits(fmaxf(acc[mi][ni][r] + bv[ni], 0.f));
#pragma unroll
            for (int s = 0; s < 2; ++s) {
                int row = s * 8 + (lane >> 3);
                int col8 = lane & 7;
                int row_g = bm + w * 32 + mi * 16 + row;
                uint4 v = *(const uint4*)&ep[row * 64 + col8 * 8];
                *(uint4*)&Cb[(size_t)row_g * ldc + bn + col8 * 8] = v;
            }
            if (mi == 0) __syncthreads();
        }
    } else {
        float* ep = (float*)(smemB + w * 4096);
#pragma unroll
        for (int mi = 0; mi < 2; ++mi) {
#pragma unroll
            for (int ni = 0; ni < 4; ++ni)
#pragma unroll
                for (int r = 0; r < 4; ++r)
                    ep[(kgrp * 4 + r) * 64 + ni * 16 + lr] = fmaxf(acc[mi][ni][r] + bv[ni], 0.f);
#pragma unroll
            for (int s = 0; s < 4; ++s) {
                int row = s * 4 + (lane >> 4);
                int colv = lane & 15;
                int row_g = bm + w * 32 + mi * 16 + row;
                int col_g = bn + colv * 4;
                if ((!MASK_ROW || row_g < M) && col_g + 4 <= N) {
                    float4 v = *(const float4*)&ep[row * 64 + colv * 4];
                    *(float4*)&Cf[(size_t)row_g * ldc + col_g] = v;
                }
            }
            if (mi == 0) __syncthreads();
        }
    }
}

// ---------------- attention: fixed-max, log2-domain, DPP reduce, bf16 T out ----------------
__global__ __launch_bounds__(256) void attn_kernel(
    const float* __restrict__ R,        // [N_HE][R_LD], scores pre-scaled by SL2E
    const float* __restrict__ q_t,      // [1489][64]
    const int2* __restrict__ rows2_all, // [3][N_HE] group-relative (start,end)
    const int* __restrict__ ebuf_all,   // [3][NBIN*BINCAP], holds d<<8 byte offsets
    bf16* __restrict__ T)               // [M_PAD][192] bf16
{
    int wid = blockIdx.x * 4 + (threadIdx.x >> 6);
    int lane = threadIdx.x & 63;
    int g = wid / N_HE;
    int h = wid - g * N_HE;
    const int toff_tab[3] = {0, 167, 1048};
    const char* qb = (const char*)(q_t + (size_t)toff_tab[g] * Q_DIM);
    const int* ebuf = ebuf_all + (size_t)g * NBIN * BINCAP;
    int2 se = rows2_all[g * N_HE + h];
    int start = se.x, end = se.y;

    int sub = lane >> 4, sl = lane & 15;
    const float* Rrow = R + (size_t)h * R_LD + g * 72;
    float4 r4 = *reinterpret_cast<const float4*>(Rrow + sl * 4);
    float ch = Rrow[64];
    int slo = sl * 16;

    float denom = 0.f;
    float acc0 = 0.f, acc1 = 0.f, acc2 = 0.f, acc3 = 0.f;

    for (int i0 = start + sub * 2; i0 < end; i0 += 8) {
        bool ok1 = (i0 + 1) < end;
        int o0 = ebuf[i0];
        int o1 = ebuf[ok1 ? i0 + 1 : i0];
        float4 t0 = *reinterpret_cast<const float4*>(qb + o0 + slo);
        float4 t1 = *reinterpret_cast<const float4*>(qb + o1 + slo);
        float p0 = t0.x * r4.x;
        p0 = fmaf(t0.y, r4.y, p0); p0 = fmaf(t0.z, r4.z, p0); p0 = fmaf(t0.w, r4.w, p0);
        float p1 = t1.x * r4.x;
        p1 = fmaf(t1.y, r4.y, p1); p1 = fmaf(t1.z, r4.z, p1); p1 = fmaf(t1.w, r4.w, p1);
        p0 = red16(p0);
        p1 = red16(p1);
        float s0 = p0 + ch; s0 = fmaxf(s0, 0.01f * s0);   // leaky_relu (pre-scaled)
        float s1 = p1 + ch; s1 = fmaxf(s1, 0.01f * s1);
        float w0 = exp2_fast(s0);
        float w1 = ok1 ? exp2_fast(s1) : 0.f;
        denom += w0 + w1;
        acc0 = fmaf(w0, t0.x, fmaf(w1, t1.x, acc0));
        acc1 = fmaf(w0, t0.y, fmaf(w1, t1.y, acc1));
        acc2 = fmaf(w0, t0.z, fmaf(w1, t1.z, acc2));
        acc3 = fmaf(w0, t0.w, fmaf(w1, t1.w, acc3));
    }

    // cross-subgroup LANE-WISE sums (lane i <-> i^16, i^32)
    denom += __shfl_xor(denom, 16, 64); denom += __shfl_xor(denom, 32, 64);
    acc0 += __shfl_xor(acc0, 16, 64); acc0 += __shfl_xor(acc0, 32, 64);
    acc1 += __shfl_xor(acc1, 16, 64); acc1 += __shfl_xor(acc1, 32, 64);
    acc2 += __shfl_xor(acc2, 16, 64); acc2 += __shfl_xor(acc2, 32, 64);
    acc3 += __shfl_xor(acc3, 16, 64); acc3 += __shfl_xor(acc3, 32, 64);
    if (sub == 0) {
        float rden = 1.f / fmaxf(denom, 1e-20f);
        ushort4 o;
        o.x = bf16bits(acc0 * rden);
        o.y = bf16bits(acc1 * rden);
        o.z = bf16bits(acc2 * rden);
        o.w = bf16bits(acc3 * rden);
        *reinterpret_cast<ushort4*>(T + (size_t)h * T_STRIDE + g * 64 + sl * 4) = o;
    }
}

// ---------------- launch ----------------
extern "C" void kernel_launch(void* const* d_in, const int* in_sizes, int n_in,
                              void* d_out, int out_size, void* d_ws, size_t ws_size,
                              hipStream_t stream)
{
    const float* he_feat = (const float*)d_in[0];
    float* out = (float*)d_out;

    EdgeIdx Esrc, Edst;
    for (int g = 0; g < 3; ++g) {
        Esrc.p[g] = (const int*)d_in[34 + 2 * g];
        Edst.p[g] = (const int*)d_in[35 + 2 * g];
    }

    char* base = (char*)d_ws;
    size_t off = 0;
    auto alloc = [&](size_t bytes) -> void* {
        void* r = (void*)(base + off);
        off = (off + bytes + 255) & ~(size_t)255;
        return r;
    };
    // ---- persistent small region (~1.5 MB) ----
    bf16* WRt_hi = (bf16*)alloc(256 * KP_HE * 2);
    bf16* WRt_lo = (bf16*)alloc(256 * KP_HE * 2);
    float* bR = (float*)alloc(R_STRIDE * 4);
    bf16* Wct_hi = (bf16*)alloc(256 * T_STRIDE * 2);
    bf16* Wct_lo = (bf16*)alloc(256 * T_STRIDE * 2);
    float* b_comp = (float*)alloc(256 * 4);
    bf16* Wm2t_hi = (bf16*)alloc(128 * 256 * 2);
    bf16* Wm2t_lo = (bf16*)alloc(128 * 256 * 2);
    float* q_t = (float*)alloc(N_NODES * Q_DIM * 4);
    int* bincursor = (int*)alloc(3 * NBIN * 4);
    int2* rows2 = (int2*)alloc((size_t)3 * N_HE * 8);
    // ---- big buffers with lifetime overlays (~82 MB total) ----
    size_t T_start = off;
    bf16* T = (bf16*)alloc((size_t)M_PAD * T_STRIDE * 2);      // 19.2 MB [attn -> mlp1]
    size_t R_start = off;
    float* R = (float*)alloc((size_t)N_HE * R_LD * 4);         // 44.8 MB [R-gemm -> attn]
    int* ebuf = (int*)alloc((size_t)3 * NBIN * BINCAP * 4);    // 15.4 MB [csr -> attn]
    // overlays:
    unsigned* binbuf = (unsigned*)(base + T_start);             // 15.4 MB [scatter -> csr]
    bf16* h1 = (bf16*)(base + R_start);                         // 25.6 MB [mlp1 -> mlp2], over dead R

    hipMemsetAsync(bincursor, 0, 3 * NBIN * 4, stream);

    // ---- fused scatter + prep ----
    PrepArgs P;
    P.w1w = (const float*)d_in[4]; P.w1b = (const float*)d_in[5];
    P.w2w = (const float*)d_in[6]; P.w2b = (const float*)d_in[7];
    for (int g = 0; g < 3; ++g) {
        P.w6[g] = (const float*)d_in[18 + 4 * g];
        P.b6[g] = (const float*)d_in[19 + 4 * g];
        P.w7[g] = (const float*)d_in[20 + 4 * g];
        P.b7[g] = (const float*)d_in[21 + 4 * g];
        P.feat[g] = (const float*)d_in[1 + g];
        P.w5[g] = (const float*)d_in[12 + 2 * g];
        P.b5[g] = (const float*)d_in[13 + 2 * g];
    }
    P.WRt_hi = WRt_hi; P.WRt_lo = WRt_lo; P.bR = bR;
    P.mlp1w = (const float*)d_in[30]; P.mlp1b = (const float*)d_in[31];
    P.Wct_hi = Wct_hi; P.Wct_lo = Wct_lo; P.b_comp = b_comp;
    P.mlp2w = (const float*)d_in[32];
    P.Wm2t_hi = Wm2t_hi; P.Wm2t_lo = Wm2t_lo;
    P.q_t = q_t;
    scatter_prep_fused_kernel<<<SCAT_BLKS + PREP_BLKS, 256, 0, stream>>>(
        Esrc, Edst, bincursor, binbuf, P);

    // ---- fused R-gemm (first) + CSR finalize (tail) ----
    csr_gemm_fused_kernel<<<MB * 4 + 3 * NBIN, 256, 0, stream>>>(
        binbuf, bincursor, rows2, ebuf, he_feat, WRt_hi, WRt_lo, bR, R);

    // ---- attention -> T bf16 (overwrites binbuf: dead) ----
    attn_kernel<<<(3 * N_HE) / 4, 256, 0, stream>>>(R, q_t, rows2, ebuf, T);

    const float* mlp2b = (const float*)d_in[33];
    // h1 = relu(T @ W_comp + b_comp) -> bf16 [M_PAD][256]  (overwrites R: dead)
    mfma_gemm_bf16A_kernel<true, false><<<MB * 4, 256, 0, stream>>>(
        4, T, T_STRIDE, T_STRIDE, Wct_hi, Wct_lo, b_comp, nullptr, h1, M_PAD, 256, 256);
    // out = relu(h1 @ mlp2w + mlp2b) -> f32 [N_HE][128]
    mfma_gemm_bf16A_kernel<false, true><<<MB * 2, 256, 0, stream>>>(
        2, h1, 256, 256, Wm2t_hi, Wm2t_lo, mlp2b, out, nullptr, N_HE, E_DIM, E_DIM);
}

// Round 19
// 238.526 us; speedup vs baseline: 1.2502x; 1.2502x over previous
//
#include <hip/hip_runtime.h>
#include <hip/hip_bf16.h>

typedef __hip_bfloat16 bf16;
typedef float f32x4 __attribute__((ext_vector_type(4)));
typedef short bf16x8s __attribute__((ext_vector_type(8)));
typedef unsigned short u16x8 __attribute__((ext_vector_type(8)));

constexpr int N_HE = 50000;
constexpr int M_PAD = 50048;           // 391 * 128
constexpr int E_EDGES = 1200000;
constexpr int IN_F = 200;
constexpr int KP_HE = 224;             // 200 padded to x32
constexpr int HE_DIM = 512;
constexpr int E_DIM = 128;
constexpr int Q_DIM = 64;
constexpr float SL2E = 0.125f * 1.44269504088896f; // SCALE * log2(e), folded into W_R/bR
constexpr int N_NODES = 1489;
constexpr int R_STRIDE = 216;          // valid R cols: 3 x 72 (64 r + 1 c + 7 pad)
constexpr int R_LD = 224;              // R row stride (floats): 896 B, 64B-aligned rows
constexpr int T_STRIDE = 192;          // 3 x 64
constexpr int LDSD = 40;               // LDS row stride (bf16): 80B
constexpr int NBIN = 98;               // ceil(50000/512) bins per group
constexpr int BIN_SHIFT = 9;           // 512 hyperedges per bin
constexpr int ECHUNK = 4096;           // edges per scatter block
constexpr int NCHUNK = (E_EDGES + ECHUNK - 1) / ECHUNK; // 293
constexpr int BINCAP = 13056;          // mean 12288 + 7 sigma, clamp-guarded
constexpr int SCAT_BLKS = 3 * NCHUNK;  // 879
constexpr int PREP_BLKS = 256 + 193 + 128 + N_NODES; // 2066
constexpr int MB = M_PAD / 128;        // 391

struct EdgeIdx { const int* p[3]; };

__device__ __forceinline__ void split2(float v, bf16& h, bf16& l)
{
    bf16 hb = __float2bfloat16(v);
    h = hb;
    l = __float2bfloat16(v - __bfloat162float(hb));
}
__device__ __forceinline__ void split2u(float v, unsigned short& h, unsigned short& l)
{
    bf16 hb = __float2bfloat16(v);
    bf16 lb = __float2bfloat16(v - __bfloat162float(hb));
    h = *reinterpret_cast<unsigned short*>(&hb);
    l = *reinterpret_cast<unsigned short*>(&lb);
}
__device__ __forceinline__ unsigned short bf16bits(float v)
{
    bf16 b = __float2bfloat16(v);
    return *reinterpret_cast<unsigned short*>(&b);
}
__device__ __forceinline__ float exp2_fast(float x)
{
    float r;
    asm("v_exp_f32 %0, %1" : "=v"(r) : "v"(x));
    return r;
}
// 16-lane (DPP-row) sum reduction, pure VALU. All lanes get the row sum.
__device__ __forceinline__ float red16(float x)
{
    x += __int_as_float(__builtin_amdgcn_update_dpp(0, __float_as_int(x), 0xB1, 0xF, 0xF, true));
    x += __int_as_float(__builtin_amdgcn_update_dpp(0, __float_as_int(x), 0x4E, 0xF, 0xF, true));
    x += __int_as_float(__builtin_amdgcn_update_dpp(0, __float_as_int(x), 0x141, 0xF, 0xF, true));
    x += __int_as_float(__builtin_amdgcn_update_dpp(0, __float_as_int(x), 0x140, 0xF, 0xF, true));
    return x;
}
// XCD-locality swizzle: all `nby` blocks sharing one A-tile get equal q mod 8 -> same XCD.
__device__ __forceinline__ void xcd_swizzle(int q, int total, int nby, int& bx, int& by)
{
    int grpsz = 8 * nby;
    int full = (total / grpsz) * grpsz;
    if (q < full) {
        bx = (q / grpsz) * 8 + (q & 7);
        by = (q >> 3) % nby;
    } else {
        int t = q - full;
        bx = full / nby + t / nby;
        by = t % nby;
    }
}

// ================= fused: bin_scatter (879 blocks) + prep (2066 blocks) =================
struct PrepArgs {
    const float *w1w, *w1b, *w2w, *w2b;
    const float *w6[3], *b6[3];
    bf16 *WRt_hi, *WRt_lo;
    float *bR;
    const float *w7[3], *b7[3];
    const float *mlp1w, *mlp1b;
    bf16 *Wct_hi, *Wct_lo;
    float *b_comp;
    const float *mlp2w;
    bf16 *Wm2t_hi, *Wm2t_lo;
    const float *feat[3], *w5[3], *b5[3];
    float *q_t;
};

__global__ __launch_bounds__(256) void scatter_prep_fused_kernel(
    EdgeIdx S, EdgeIdx D, int* __restrict__ bincursor, unsigned* __restrict__ binbuf,
    PrepArgs P)
{
    __shared__ unsigned stage[ECHUNK];
    __shared__ int hist4[4][NBIN];
    __shared__ int hist[NBIN], off[NBIN], cur[NBIN], gbase[NBIN];
    int bid = blockIdx.x, tid = threadIdx.x;
    if (bid < SCAT_BLKS) {
        // ---------------- bin_scatter ----------------
        int g = bid / NCHUNK, chunk = bid - g * NCHUNK;
        const int* src = S.p[g];
        const int* dst = D.p[g];
        int lane = tid & 63, w = tid >> 6;
        for (int b = tid; b < 4 * NBIN; b += 256) (&hist4[0][0])[b] = 0;
        __syncthreads();
        int base = chunk * ECHUNK;
        int s[ECHUNK / 256], d[ECHUNK / 256];
#pragma unroll
        for (int k = 0; k < ECHUNK / 256; ++k) {
            int i = base + k * 256 + tid;
            if (i < E_EDGES) {
                s[k] = src[i];
                d[k] = dst[i];
                atomicAdd(&hist4[w][s[k] >> BIN_SHIFT], 1);
            } else s[k] = -1;
        }
        __syncthreads();
        if (w == 0) {
            int i1 = 64 + lane;
            int v0 = 0, v1 = 0;
            if (lane < NBIN) v0 = hist4[0][lane] + hist4[1][lane] + hist4[2][lane] + hist4[3][lane];
            if (i1 < NBIN) v1 = hist4[0][i1] + hist4[1][i1] + hist4[2][i1] + hist4[3][i1];
            int x0 = v0, x1 = v1;
#pragma unroll
            for (int o = 1; o < 64; o <<= 1) {
                int t0 = __shfl_up(x0, o, 64);
                int t1 = __shfl_up(x1, o, 64);
                if (lane >= o) { x0 += t0; x1 += t1; }
            }
            int tot0 = __shfl(x0, 63, 64);
            if (lane < NBIN) { hist[lane] = v0; off[lane] = x0 - v0; cur[lane] = x0 - v0; }
            if (i1 < NBIN) { hist[i1] = v1; off[i1] = tot0 + x1 - v1; cur[i1] = tot0 + x1 - v1; }
        }
        __syncthreads();
        if (tid < NBIN) gbase[tid] = hist[tid] ? atomicAdd(&bincursor[g * NBIN + tid], hist[tid]) : 0;
        __syncthreads();
#pragma unroll
        for (int k = 0; k < ECHUNK / 256; ++k) {
            if (s[k] >= 0) {
                int bin = s[k] >> BIN_SHIFT;
                int pos = atomicAdd(&cur[bin], 1);
                stage[pos] = ((unsigned)(s[k] & 511) << 10) | (unsigned)d[k];
            }
        }
        __syncthreads();
        size_t gslot = (size_t)g * NBIN * BINCAP;
        for (int b = w; b < NBIN; b += 4) {
            int len = hist[b];
            if (!len) continue;
            int gb = gbase[b];
            int avail = BINCAP - gb;
            if (avail <= 0) continue;
            if (len > avail) len = avail;
            int lo = off[b];
            size_t obase = gslot + (size_t)b * BINCAP + gb;
            for (int j = lane; j < len; j += 64)
                binbuf[obase + j] = stage[lo + j];
        }
        return;
    }
    // ---------------- prep (reuses `stage` LDS as float scratch) ----------------
    float* sh = (float*)stage;
    int pb = bid - SCAT_BLKS;
    if (pb < 256) {
        // W_R column c: bkv_c -> M2 = w2w@bkv_c -> W_R[:,c] = w1w@M2 (*SL2E); bR_c
        int c = pb;
        const bf16 z = __float2bfloat16(0.f);
        if (c >= R_STRIDE) {
            if (tid < KP_HE) { P.WRt_hi[c * KP_HE + tid] = z; P.WRt_lo[c * KP_HE + tid] = z; }
            return;
        }
        float* bkv = sh;          // [128]
        float* M2 = sh + 128;     // [512]
        float* psum = sh + 640;   // [32]
        int g = c / 72, j = c - g * 72;
        if (tid < 128) {
            float v = 0.f;
            if (j < 64) v = P.w6[g][j * E_DIM + tid];
            else if (j == 64) v = P.b6[g][tid];
            bkv[tid] = v;
        }
        __syncthreads();
        for (int h = tid; h < HE_DIM; h += 256) {
            const float* w2row = P.w2w + (size_t)h * E_DIM;
            float s = 0.f;
#pragma unroll 4
            for (int k = 0; k < 128; ++k) s = fmaf(w2row[k], bkv[k], s);
            M2[h] = s;
        }
        __syncthreads();
        if (tid < IN_F) {
            const float* w1row = P.w1w + (size_t)tid * HE_DIM;
            float s = 0.f;
#pragma unroll 4
            for (int h = 0; h < HE_DIM; ++h) s = fmaf(w1row[h], M2[h], s);
            bf16 hh, ll; split2(s * SL2E, hh, ll);
            P.WRt_hi[c * KP_HE + tid] = hh;
            P.WRt_lo[c * KP_HE + tid] = ll;
        } else if (tid < KP_HE) {
            P.WRt_hi[c * KP_HE + tid] = z;
            P.WRt_lo[c * KP_HE + tid] = z;
        } else {
            int l = tid - 224; // 0..31
            float s = 0.f;
#pragma unroll 4
            for (int h = l * 16; h < l * 16 + 16; ++h) s = fmaf(P.w1b[h], M2[h], s);
#pragma unroll
            for (int k = l * 4; k < l * 4 + 4; ++k) s = fmaf(P.w2b[k], bkv[k], s);
            psum[l] = s;
        }
        __syncthreads();
        if (tid == 224) {
            float s = 0.f;
#pragma unroll
            for (int l = 0; l < 32; ++l) s += psum[l];
            P.bR[c] = s * SL2E;
        }
    } else if (pb < 449) {
        // Wct^T hi/lo [256][192]; row 192 -> b_comp
        int row = pb - 256;
        int n = tid;
        if (row < 192) {
            int g = row >> 6, i = row & 63;
            const float* w7 = P.w7[g];
            float s = 0.f;
#pragma unroll 4
            for (int k = 0; k < 128; ++k)
                s = fmaf(w7[i * 128 + k], P.mlp1w[(size_t)(g * 128 + k) * 256 + n], s);
            bf16 h, l; split2(s, h, l);
            P.Wct_hi[n * T_STRIDE + row] = h;
            P.Wct_lo[n * T_STRIDE + row] = l;
        } else {
            float s = P.mlp1b[n];
            for (int g = 0; g < 3; ++g)
#pragma unroll 4
                for (int k = 0; k < 128; ++k)
                    s = fmaf(P.b7[g][k], P.mlp1w[(size_t)(g * 128 + k) * 256 + n], s);
            P.b_comp[n] = s;
        }
    } else if (pb < 577) {
        // mlp2w^T hi/lo [128][256]
        int n = pb - 449;
        int k = tid;
        float v = P.mlp2w[(size_t)k * 128 + n];
        bf16 h, l; split2(v, h, l);
        P.Wm2t_hi[n * 256 + k] = h;
        P.Wm2t_lo[n * 256 + k] = l;
    } else {
        // node q projection: one block per node row
        int b = pb - 577; // 0..1488
        int g = (b < 167) ? 0 : (b < 1048 ? 1 : 2);
        int row = b - (g == 0 ? 0 : (g == 1 ? 167 : 1048));
        int Dt = (g == 0) ? 167 : (g == 1 ? 881 : 441);
        const float* feat = P.feat[g] + (size_t)row * Dt;
        const float* w5 = P.w5[g];
        int col = tid & 63, ks = tid >> 6;
        float s = 0.f;
#pragma unroll 4
        for (int k = ks; k < Dt; k += 4)
            s = fmaf(feat[k], w5[k * Q_DIM + col], s);
        sh[ks * 64 + col] = s;
        __syncthreads();
        if (ks == 0)
            P.q_t[(size_t)b * Q_DIM + col] =
                sh[col] + sh[64 + col] + sh[128 + col] + sh[192 + col] + P.b5[g][col];
    }
}

// ---------------- f32-A split-3-pass MFMA GEMM body (reg prefetch, LDS-staged A+B, LDS-transpose epilogue) ----------------
__device__ __forceinline__ void gemm_f32A_body(
    char* smem, int bx, int by, int tid,
    const float* __restrict__ A, int lda, int Kp, int Mvalid,
    const bf16* __restrict__ Bthg, const bf16* __restrict__ Btlg,
    const float* __restrict__ bias,
    float* __restrict__ C, int M, int N, int ldc)
{
    bf16* Ah = (bf16*)smem;
    bf16* Al = Ah + 128 * LDSD;
    bf16* Bh = Al + 128 * LDSD;
    bf16* Bl = Bh + 64 * LDSD;
    const int bm = bx * 128, bn = by * 64;
    const int lane = tid & 63, w = tid >> 6;
    const int kgrp = lane >> 4, lr = lane & 15;
    const int arow = tid >> 1, ahalf = (tid & 1) * 16;
    const int brow = tid >> 2, bq = (tid & 3) * 8;
    f32x4 acc[2][4] = {};

    float va[16];
    uint4 vb0, vb1;
    const int arowg = bm + arow;

    // prologue loads (k0 = 0)
    {
        int kb = ahalf;
        if (arowg < Mvalid && kb + 16 <= lda) {
            const float* ap = A + (size_t)arowg * lda + kb;
            *(float4*)&va[0]  = *(const float4*)ap;
            *(float4*)&va[4]  = *(const float4*)(ap + 4);
            *(float4*)&va[8]  = *(const float4*)(ap + 8);
            *(float4*)&va[12] = *(const float4*)(ap + 12);
        } else {
#pragma unroll
            for (int j = 0; j < 16; ++j) {
                int k = kb + j;
                va[j] = (arowg < Mvalid && k < lda) ? A[(size_t)arowg * lda + k] : 0.f;
            }
        }
        const size_t bbase = (size_t)(bn + brow) * Kp + bq;
        vb0 = *(const uint4*)(Bthg + bbase);
        vb1 = *(const uint4*)(Btlg + bbase);
    }

    for (int k0 = 0; k0 < Kp; k0 += 32) {
        {
            u16x8 H0, H1, L0, L1;
#pragma unroll
            for (int j = 0; j < 8; ++j) {
                unsigned short h, l;
                split2u(va[j], h, l);       H0[j] = h; L0[j] = l;
                split2u(va[8 + j], h, l);   H1[j] = h; L1[j] = l;
            }
            *(u16x8*)&Ah[arow * LDSD + ahalf] = H0;
            *(u16x8*)&Ah[arow * LDSD + ahalf + 8] = H1;
            *(u16x8*)&Al[arow * LDSD + ahalf] = L0;
            *(u16x8*)&Al[arow * LDSD + ahalf + 8] = L1;
            *(uint4*)&Bh[brow * LDSD + bq] = vb0;
            *(uint4*)&Bl[brow * LDSD + bq] = vb1;
        }
        if (k0 + 32 < Kp) {
            int kb = k0 + 32 + ahalf;
            if (arowg < Mvalid && kb + 16 <= lda) {
                const float* ap = A + (size_t)arowg * lda + kb;
                *(float4*)&va[0]  = *(const float4*)ap;
                *(float4*)&va[4]  = *(const float4*)(ap + 4);
                *(float4*)&va[8]  = *(const float4*)(ap + 8);
                *(float4*)&va[12] = *(const float4*)(ap + 12);
            } else {
#pragma unroll
                for (int j = 0; j < 16; ++j) {
                    int k = kb + j;
                    va[j] = (arowg < Mvalid && k < lda) ? A[(size_t)arowg * lda + k] : 0.f;
                }
            }
            const size_t bbase = (size_t)(bn + brow) * Kp + k0 + 32 + bq;
            vb0 = *(const uint4*)(Bthg + bbase);
            vb1 = *(const uint4*)(Btlg + bbase);
        }
        __syncthreads();
        bf16x8s afh[2], afl[2], bfh[4], bfl[4];
#pragma unroll
        for (int mi = 0; mi < 2; ++mi) {
            int r = w * 32 + mi * 16 + lr;
            afh[mi] = *(const bf16x8s*)&Ah[r * LDSD + kgrp * 8];
            afl[mi] = *(const bf16x8s*)&Al[r * LDSD + kgrp * 8];
        }
#pragma unroll
        for (int ni = 0; ni < 4; ++ni) {
            int r = ni * 16 + lr;
            bfh[ni] = *(const bf16x8s*)&Bh[r * LDSD + kgrp * 8];
            bfl[ni] = *(const bf16x8s*)&Bl[r * LDSD + kgrp * 8];
        }
#pragma unroll
        for (int mi = 0; mi < 2; ++mi)
#pragma unroll
            for (int ni = 0; ni < 4; ++ni) {
                acc[mi][ni] = __builtin_amdgcn_mfma_f32_16x16x32_bf16(afh[mi], bfh[ni], acc[mi][ni], 0, 0, 0);
                acc[mi][ni] = __builtin_amdgcn_mfma_f32_16x16x32_bf16(afl[mi], bfh[ni], acc[mi][ni], 0, 0, 0);
                acc[mi][ni] = __builtin_amdgcn_mfma_f32_16x16x32_bf16(afh[mi], bfl[ni], acc[mi][ni], 0, 0, 0);
            }
        __syncthreads();
    }

    // LDS-transpose epilogue: full-line float4 stores (per-wave 4KB region)
    float* ep = (float*)(smem + w * 4096);
    float bv[4];
#pragma unroll
    for (int ni = 0; ni < 4; ++ni) {
        int col = bn + ni * 16 + lr;
        bv[ni] = (col < N) ? bias[col] : 0.f;
    }
    __syncthreads();
#pragma unroll
    for (int mi = 0; mi < 2; ++mi) {
#pragma unroll
        for (int ni = 0; ni < 4; ++ni)
#pragma unroll
            for (int r = 0; r < 4; ++r)
                ep[(kgrp * 4 + r) * 64 + ni * 16 + lr] = acc[mi][ni][r] + bv[ni];
#pragma unroll
        for (int s = 0; s < 4; ++s) {
            int row = s * 4 + (lane >> 4);
            int colv = lane & 15;
            int row_g = bm + w * 32 + mi * 16 + row;
            int col_g = bn + colv * 4;
            if (row_g < M && col_g + 4 <= N) {
                float4 v = *(const float4*)&ep[row * 64 + colv * 4];
                *(float4*)&C[(size_t)row_g * ldc + col_g] = v;
            }
        }
        if (mi == 0) __syncthreads();
    }
}

// ---------------- fused: R-gemm FIRST (1564 blocks, XCD-swizzled) + bin_csr (294 tail blocks) ----------------
__global__ __launch_bounds__(256) void csr_gemm_fused_kernel(
    const unsigned* __restrict__ binbuf, const int* __restrict__ bincursor,
    int2* __restrict__ rows2_all, int* __restrict__ ebuf,
    const float* __restrict__ he_feat,
    const bf16* __restrict__ WRt_hi, const bf16* __restrict__ WRt_lo,
    const float* __restrict__ bR, float* __restrict__ R)
{
    __shared__ __attribute__((aligned(16))) char smem[30720];
    int bid = blockIdx.x, tid = threadIdx.x;
    if (bid < MB * 4) {
        int bx, by;
        xcd_swizzle(bid, MB * 4, 4, bx, by);
        gemm_f32A_body(smem, bx, by, tid,
                       he_feat, IN_F, KP_HE, N_HE, WRt_hi, WRt_lo, bR,
                       R, N_HE, R_STRIDE, R_LD);
    } else {
        int cid = bid - MB * 4;
        int* hist = (int*)smem;
        int* cur = hist + 512;
        int* cs = cur + 512;
        int g = cid / NBIN, b = cid - g * NBIN;
        int cnt = min(bincursor[g * NBIN + b], BINCAP);
        size_t sbase = ((size_t)g * NBIN + b) * BINCAP;
        int h0 = b << BIN_SHIFT;
        int hN = min(512, N_HE - h0);
        int ebase_rel = b * BINCAP;
        int2* rows2 = rows2_all + g * N_HE;
        int lane = tid & 63, w = tid >> 6;
        hist[tid] = 0; hist[tid + 256] = 0;
        __syncthreads();
        for (int i = tid; i < cnt; i += 256)
            atomicAdd(&hist[binbuf[sbase + i] >> 10], 1);
        __syncthreads();
#pragma unroll
        for (int c2 = 0; c2 < 2; ++c2) {
            int c = w * 2 + c2, idx = c * 64 + lane;
            int v = hist[idx], x = v;
#pragma unroll
            for (int o = 1; o < 64; o <<= 1) {
                int t = __shfl_up(x, o, 64);
                if (lane >= o) x += t;
            }
            cur[idx] = x - v;
            if (lane == 63) cs[c] = x;
        }
        __syncthreads();
        if (tid == 0) {
            int run = 0;
#pragma unroll
            for (int c = 0; c < 8; ++c) { int t = cs[c]; cs[c] = run; run += t; }
        }
        __syncthreads();
#pragma unroll
        for (int c2 = 0; c2 < 2; ++c2) {
            int c = w * 2 + c2, idx = c * 64 + lane;
            int e = cur[idx] + cs[c];
            cur[idx] = e;
            if (idx < hN) rows2[h0 + idx] = make_int2(ebase_rel + e, ebase_rel + e + hist[idx]);
        }
        __syncthreads();
        for (int i = tid; i < cnt; i += 256) {
            unsigned p = binbuf[sbase + i];
            int pos = atomicAdd(&cur[p >> 10], 1);
            ebuf[sbase + pos] = (int)((p & 1023u) << 8); // byte offset into q_t rows (256 B/row)
        }
    }
}

// ---------------- bf16-A 2-pass MFMA GEMM, XCD swizzle, reg prefetch, LDS-transpose epilogue ----------------
template <bool OUT_BF16, bool MASK_ROW>
__global__ __launch_bounds__(256) void mfma_gemm_bf16A_kernel(
    int nby,
    const bf16* __restrict__ A, int lda, int Kp,
    const bf16* __restrict__ Bthg, const bf16* __restrict__ Btlg,
    const float* __restrict__ bias,
    float* __restrict__ Cf, bf16* __restrict__ Cb,
    int M, int N, int ldc)
{
    __shared__ __attribute__((aligned(16))) char smemB[20480];
    bf16* Ah = (bf16*)smemB;
    bf16* Bh = Ah + 128 * LDSD;
    bf16* Bl = Bh + 64 * LDSD;
    const int tid = threadIdx.x;
    int bx, by;
    xcd_swizzle(blockIdx.x, gridDim.x, nby, bx, by);
    const int bm = bx * 128, bn = by * 64;
    const int lane = tid & 63, w = tid >> 6;
    const int kgrp = lane >> 4, lr = lane & 15;
    const int arow = tid >> 1, ahalf = (tid & 1) * 16;
    const int brow = tid >> 2, bq = (tid & 3) * 8;
    f32x4 acc[2][4] = {};

    uint4 ra0, ra1, rb0, rb1;
    {
        const bf16* ap = A + (size_t)(bm + arow) * lda + ahalf;
        ra0 = *(const uint4*)ap;
        ra1 = *(const uint4*)(ap + 8);
        const size_t bbase = (size_t)(bn + brow) * Kp + bq;
        rb0 = *(const uint4*)(Bthg + bbase);
        rb1 = *(const uint4*)(Btlg + bbase);
    }

    for (int k0 = 0; k0 < Kp; k0 += 32) {
        *(uint4*)&Ah[arow * LDSD + ahalf] = ra0;
        *(uint4*)&Ah[arow * LDSD + ahalf + 8] = ra1;
        *(uint4*)&Bh[brow * LDSD + bq] = rb0;
        *(uint4*)&Bl[brow * LDSD + bq] = rb1;
        if (k0 + 32 < Kp) {
            const bf16* ap = A + (size_t)(bm + arow) * lda + k0 + 32 + ahalf;
            ra0 = *(const uint4*)ap;
            ra1 = *(const uint4*)(ap + 8);
            const size_t bbase = (size_t)(bn + brow) * Kp + k0 + 32 + bq;
            rb0 = *(const uint4*)(Bthg + bbase);
            rb1 = *(const uint4*)(Btlg + bbase);
        }
        __syncthreads();
        bf16x8s afh[2], bfh[4], bfl[4];
#pragma unroll
        for (int mi = 0; mi < 2; ++mi) {
            int r = w * 32 + mi * 16 + lr;
            afh[mi] = *(const bf16x8s*)&Ah[r * LDSD + kgrp * 8];
        }
#pragma unroll
        for (int ni = 0; ni < 4; ++ni) {
            int r = ni * 16 + lr;
            bfh[ni] = *(const bf16x8s*)&Bh[r * LDSD + kgrp * 8];
            bfl[ni] = *(const bf16x8s*)&Bl[r * LDSD + kgrp * 8];
        }
#pragma unroll
        for (int mi = 0; mi < 2; ++mi)
#pragma unroll
            for (int ni = 0; ni < 4; ++ni) {
                acc[mi][ni] = __builtin_amdgcn_mfma_f32_16x16x32_bf16(afh[mi], bfh[ni], acc[mi][ni], 0, 0, 0);
                acc[mi][ni] = __builtin_amdgcn_mfma_f32_16x16x32_bf16(afh[mi], bfl[ni], acc[mi][ni], 0, 0, 0);
            }
        __syncthreads();
    }

    // LDS-transpose epilogue (per-wave 4KB region)
    float bv[4];
#pragma unroll
    for (int ni = 0; ni < 4; ++ni) {
        int col = bn + ni * 16 + lr;
        bv[ni] = (col < N) ? bias[col] : 0.f;
    }
    __syncthreads();
    if (OUT_BF16) {
        unsigned short* ep = (unsigned short*)(smemB + w * 4096);
#pragma unroll
        for (int mi = 0; mi < 2; ++mi) {
#pragma unroll
            for (int ni = 0; ni < 4; ++ni)
#pragma unroll
                for (int r = 0; r < 4; ++r)
                    ep[(kgrp * 4 + r) * 64 + ni * 16 + lr] = bf16bits(fmaxf(acc[mi][ni][r] + bv[ni], 0.f));
#pragma unroll
            for (int s = 0; s < 2; ++s) {
                int row = s * 8 + (lane >> 3);
                int col8 = lane & 7;
                int row_g = bm + w * 32 + mi * 16 + row;
                uint4 v = *(const uint4*)&ep[row * 64 + col8 * 8];
                *(uint4*)&Cb[(size_t)row_g * ldc + bn + col8 * 8] = v;
            }
            if (mi == 0) __syncthreads();
        }
    } else {
        float* ep = (float*)(smemB + w * 4096);
#pragma unroll
        for (int mi = 0; mi < 2; ++mi) {
#pragma unroll
            for (int ni = 0; ni < 4; ++ni)
#pragma unroll
                for (int r = 0; r < 4; ++r)
                    ep[(kgrp * 4 + r) * 64 + ni * 16 + lr] = fmaxf(acc[mi][ni][r] + bv[ni], 0.f);
#pragma unroll
            for (int s = 0; s < 4; ++s) {
                int row = s * 4 + (lane >> 4);
                int colv = lane & 15;
                int row_g = bm + w * 32 + mi * 16 + row;
                int col_g = bn + colv * 4;
                if ((!MASK_ROW || row_g < M) && col_g + 4 <= N) {
                    float4 v = *(const float4*)&ep[row * 64 + colv * 4];
                    *(float4*)&Cf[(size_t)row_g * ldc + col_g] = v;
                }
            }
            if (mi == 0) __syncthreads();
        }
    }
}

// ---------------- attention: fixed-max, log2-domain, DPP reduce, bf16 T out ----------------
__global__ __launch_bounds__(256) void attn_kernel(
    const float* __restrict__ R,        // [N_HE][R_LD], scores pre-scaled by SL2E
    const float* __restrict__ q_t,      // [1489][64]
    const int2* __restrict__ rows2_all, // [3][N_HE] group-relative (start,end)
    const int* __restrict__ ebuf_all,   // [3][NBIN*BINCAP], holds d<<8 byte offsets
    bf16* __restrict__ T)               // [M_PAD][192] bf16
{
    int wid = blockIdx.x * 4 + (threadIdx.x >> 6);
    int lane = threadIdx.x & 63;
    int g = wid / N_HE;
    int h = wid - g * N_HE;
    const int toff_tab[3] = {0, 167, 1048};
    const char* qb = (const char*)(q_t + (size_t)toff_tab[g] * Q_DIM);
    const int* ebuf = ebuf_all + (size_t)g * NBIN * BINCAP;
    int2 se = rows2_all[g * N_HE + h];
    int start = se.x, end = se.y;

    int sub = lane >> 4, sl = lane & 15;
    const float* Rrow = R + (size_t)h * R_LD + g * 72;
    float4 r4 = *reinterpret_cast<const float4*>(Rrow + sl * 4);
    float ch = Rrow[64];
    int slo = sl * 16;

    float denom = 0.f;
    float acc0 = 0.f, acc1 = 0.f, acc2 = 0.f, acc3 = 0.f;

    for (int i0 = start + sub * 2; i0 < end; i0 += 8) {
        bool ok1 = (i0 + 1) < end;
        int o0 = ebuf[i0];
        int o1 = ebuf[ok1 ? i0 + 1 : i0];
        float4 t0 = *reinterpret_cast<const float4*>(qb + o0 + slo);
        float4 t1 = *reinterpret_cast<const float4*>(qb + o1 + slo);
        float p0 = t0.x * r4.x;
        p0 = fmaf(t0.y, r4.y, p0); p0 = fmaf(t0.z, r4.z, p0); p0 = fmaf(t0.w, r4.w, p0);
        float p1 = t1.x * r4.x;
        p1 = fmaf(t1.y, r4.y, p1); p1 = fmaf(t1.z, r4.z, p1); p1 = fmaf(t1.w, r4.w, p1);
        p0 = red16(p0);
        p1 = red16(p1);
        float s0 = p0 + ch; s0 = fmaxf(s0, 0.01f * s0);   // leaky_relu (pre-scaled)
        float s1 = p1 + ch; s1 = fmaxf(s1, 0.01f * s1);
        float w0 = exp2_fast(s0);
        float w1 = ok1 ? exp2_fast(s1) : 0.f;
        denom += w0 + w1;
        acc0 = fmaf(w0, t0.x, fmaf(w1, t1.x, acc0));
        acc1 = fmaf(w0, t0.y, fmaf(w1, t1.y, acc1));
        acc2 = fmaf(w0, t0.z, fmaf(w1, t1.z, acc2));
        acc3 = fmaf(w0, t0.w, fmaf(w1, t1.w, acc3));
    }

    // cross-subgroup LANE-WISE sums (lane i <-> i^16, i^32)
    denom += __shfl_xor(denom, 16, 64); denom += __shfl_xor(denom, 32, 64);
    acc0 += __shfl_xor(acc0, 16, 64); acc0 += __shfl_xor(acc0, 32, 64);
    acc1 += __shfl_xor(acc1, 16, 64); acc1 += __shfl_xor(acc1, 32, 64);
    acc2 += __shfl_xor(acc2, 16, 64); acc2 += __shfl_xor(acc2, 32, 64);
    acc3 += __shfl_xor(acc3, 16, 64); acc3 += __shfl_xor(acc3, 32, 64);
    if (sub == 0) {
        float rden = 1.f / fmaxf(denom, 1e-20f);
        ushort4 o;
        o.x = bf16bits(acc0 * rden);
        o.y = bf16bits(acc1 * rden);
        o.z = bf16bits(acc2 * rden);
        o.w = bf16bits(acc3 * rden);
        *reinterpret_cast<ushort4*>(T + (size_t)h * T_STRIDE + g * 64 + sl * 4) = o;
    }
}

// ---------------- launch ----------------
extern "C" void kernel_launch(void* const* d_in, const int* in_sizes, int n_in,
                              void* d_out, int out_size, void* d_ws, size_t ws_size,
                              hipStream_t stream)
{
    const float* he_feat = (const float*)d_in[0];
    float* out = (float*)d_out;

    EdgeIdx Esrc, Edst;
    for (int g = 0; g < 3; ++g) {
        Esrc.p[g] = (const int*)d_in[34 + 2 * g];
        Edst.p[g] = (const int*)d_in[35 + 2 * g];
    }

    char* base = (char*)d_ws;
    size_t off = 0;
    auto alloc = [&](size_t bytes) -> void* {
        void* r = (void*)(base + off);
        off = (off + bytes + 255) & ~(size_t)255;
        return r;
    };
    // ---- persistent small region (~1.5 MB) ----
    bf16* WRt_hi = (bf16*)alloc(256 * KP_HE * 2);
    bf16* WRt_lo = (bf16*)alloc(256 * KP_HE * 2);
    float* bR = (float*)alloc(R_STRIDE * 4);
    bf16* Wct_hi = (bf16*)alloc(256 * T_STRIDE * 2);
    bf16* Wct_lo = (bf16*)alloc(256 * T_STRIDE * 2);
    float* b_comp = (float*)alloc(256 * 4);
    bf16* Wm2t_hi = (bf16*)alloc(128 * 256 * 2);
    bf16* Wm2t_lo = (bf16*)alloc(128 * 256 * 2);
    float* q_t = (float*)alloc(N_NODES * Q_DIM * 4);
    int* bincursor = (int*)alloc(3 * NBIN * 4);
    int2* rows2 = (int2*)alloc((size_t)3 * N_HE * 8);
    // ---- big buffers with lifetime overlays (~82 MB total) ----
    size_t T_start = off;
    bf16* T = (bf16*)alloc((size_t)M_PAD * T_STRIDE * 2);      // 19.2 MB [attn -> mlp1]
    size_t R_start = off;
    float* R = (float*)alloc((size_t)N_HE * R_LD * 4);         // 44.8 MB [R-gemm -> attn]
    int* ebuf = (int*)alloc((size_t)3 * NBIN * BINCAP * 4);    // 15.4 MB [csr -> attn]
    // overlays:
    unsigned* binbuf = (unsigned*)(base + T_start);             // 15.4 MB [scatter -> csr]
    bf16* h1 = (bf16*)(base + R_start);                         // 25.6 MB [mlp1 -> mlp2], over dead R

    hipMemsetAsync(bincursor, 0, 3 * NBIN * 4, stream);

    // ---- fused scatter + prep ----
    PrepArgs P;
    P.w1w = (const float*)d_in[4]; P.w1b = (const float*)d_in[5];
    P.w2w = (const float*)d_in[6]; P.w2b = (const float*)d_in[7];
    for (int g = 0; g < 3; ++g) {
        P.w6[g] = (const float*)d_in[18 + 4 * g];
        P.b6[g] = (const float*)d_in[19 + 4 * g];
        P.w7[g] = (const float*)d_in[20 + 4 * g];
        P.b7[g] = (const float*)d_in[21 + 4 * g];
        P.feat[g] = (const float*)d_in[1 + g];
        P.w5[g] = (const float*)d_in[12 + 2 * g];
        P.b5[g] = (const float*)d_in[13 + 2 * g];
    }
    P.WRt_hi = WRt_hi; P.WRt_lo = WRt_lo; P.bR = bR;
    P.mlp1w = (const float*)d_in[30]; P.mlp1b = (const float*)d_in[31];
    P.Wct_hi = Wct_hi; P.Wct_lo = Wct_lo; P.b_comp = b_comp;
    P.mlp2w = (const float*)d_in[32];
    P.Wm2t_hi = Wm2t_hi; P.Wm2t_lo = Wm2t_lo;
    P.q_t = q_t;
    scatter_prep_fused_kernel<<<SCAT_BLKS + PREP_BLKS, 256, 0, stream>>>(
        Esrc, Edst, bincursor, binbuf, P);

    // ---- fused R-gemm (first) + CSR finalize (tail) ----
    csr_gemm_fused_kernel<<<MB * 4 + 3 * NBIN, 256, 0, stream>>>(
        binbuf, bincursor, rows2, ebuf, he_feat, WRt_hi, WRt_lo, bR, R);

    // ---- attention -> T bf16 (overwrites binbuf: dead) ----
    attn_kernel<<<(3 * N_HE) / 4, 256, 0, stream>>>(R, q_t, rows2, ebuf, T);

    const float* mlp2b = (const float*)d_in[33];
    // h1 = relu(T @ W_comp + b_comp) -> bf16 [M_PAD][256]  (overwrites R: dead)
    mfma_gemm_bf16A_kernel<true, false><<<MB * 4, 256, 0, stream>>>(
        4, T, T_STRIDE, T_STRIDE, Wct_hi, Wct_lo, b_comp, nullptr, h1, M_PAD, 256, 256);
    // out = relu(h1 @ mlp2w + mlp2b) -> f32 [N_HE][128]
    mfma_gemm_bf16A_kernel<false, true><<<MB * 2, 256, 0, stream>>>(
        2, h1, 256, 256, Wm2t_hi, Wm2t_lo, mlp2b, out, nullptr, N_HE, E_DIM, E_DIM);
}

// Round 20
// 231.673 us; speedup vs baseline: 1.2871x; 1.0296x over previous
//
#include <hip/hip_runtime.h>
#include <hip/hip_bf16.h>

typedef __hip_bfloat16 bf16;
typedef float f32x4 __attribute__((ext_vector_type(4)));
typedef short bf16x8s __attribute__((ext_vector_type(8)));
typedef unsigned short u16x8 __attribute__((ext_vector_type(8)));

constexpr int N_HE = 50000;
constexpr int M_PAD = 50048;           // 391 * 128
constexpr int E_EDGES = 1200000;
constexpr int IN_F = 200;
constexpr int KP_HE = 224;             // 200 padded to x32
constexpr int HE_DIM = 512;
constexpr int E_DIM = 128;
constexpr int Q_DIM = 64;
constexpr float SL2E = 0.125f * 1.44269504088896f; // SCALE * log2(e), folded into W_R/bR
constexpr int N_NODES = 1489;
constexpr int R_STRIDE = 216;          // valid R cols: 3 x 72 (64 r + 1 c + 7 pad)
constexpr int R_LD = 224;              // R row stride (floats): 896 B, 64B-aligned rows
constexpr int T_STRIDE = 192;          // 3 x 64
constexpr int LDSD = 40;               // LDS row stride (bf16): 80B
constexpr int NBIN = 98;               // ceil(50000/512) bins per group
constexpr int BIN_SHIFT = 9;           // 512 hyperedges per bin
constexpr int ECHUNK = 4096;           // edges per scatter block
constexpr int NCHUNK = (E_EDGES + ECHUNK - 1) / ECHUNK; // 293
constexpr int BINCAP = 13056;          // mean 12288 + 7 sigma, clamp-guarded
constexpr int SCAT_BLKS = 3 * NCHUNK;  // 879
constexpr int PREP_BLKS = 256 + 193 + 128 + N_NODES; // 2066
constexpr int MB = M_PAD / 128;        // 391

struct EdgeIdx { const int* p[3]; };

__device__ __forceinline__ void split2(float v, bf16& h, bf16& l)
{
    bf16 hb = __float2bfloat16(v);
    h = hb;
    l = __float2bfloat16(v - __bfloat162float(hb));
}
__device__ __forceinline__ void split2u(float v, unsigned short& h, unsigned short& l)
{
    bf16 hb = __float2bfloat16(v);
    bf16 lb = __float2bfloat16(v - __bfloat162float(hb));
    h = *reinterpret_cast<unsigned short*>(&hb);
    l = *reinterpret_cast<unsigned short*>(&lb);
}
__device__ __forceinline__ unsigned short bf16bits(float v)
{
    bf16 b = __float2bfloat16(v);
    return *reinterpret_cast<unsigned short*>(&b);
}
__device__ __forceinline__ float exp2_fast(float x)
{
    float r;
    asm("v_exp_f32 %0, %1" : "=v"(r) : "v"(x));
    return r;
}
// 16-lane (DPP-row) sum reduction, pure VALU. All lanes get the row sum.
__device__ __forceinline__ float red16(float x)
{
    x += __int_as_float(__builtin_amdgcn_update_dpp(0, __float_as_int(x), 0xB1, 0xF, 0xF, true));
    x += __int_as_float(__builtin_amdgcn_update_dpp(0, __float_as_int(x), 0x4E, 0xF, 0xF, true));
    x += __int_as_float(__builtin_amdgcn_update_dpp(0, __float_as_int(x), 0x141, 0xF, 0xF, true));
    x += __int_as_float(__builtin_amdgcn_update_dpp(0, __float_as_int(x), 0x140, 0xF, 0xF, true));
    return x;
}
// XCD-locality swizzle: all `nby` blocks sharing one A-tile get equal q mod 8 -> same XCD.
__device__ __forceinline__ void xcd_swizzle(int q, int total, int nby, int& bx, int& by)
{
    int grpsz = 8 * nby;
    int full = (total / grpsz) * grpsz;
    if (q < full) {
        bx = (q / grpsz) * 8 + (q & 7);
        by = (q >> 3) % nby;
    } else {
        int t = q - full;
        bx = full / nby + t / nby;
        by = t % nby;
    }
}

// ================= fused: bin_scatter (879 blocks) + prep (2066 blocks) =================
struct PrepArgs {
    const float *w1w, *w1b, *w2w, *w2b;
    const float *w6[3], *b6[3];
    bf16 *WRt_hi, *WRt_lo;
    float *bR;
    const float *w7[3], *b7[3];
    const float *mlp1w, *mlp1b;
    bf16 *Wct_hi, *Wct_lo;
    float *b_comp;
    const float *mlp2w;
    bf16 *Wm2t_hi, *Wm2t_lo;
    const float *feat[3], *w5[3], *b5[3];
    float *q_t;
};

__global__ __launch_bounds__(256) void scatter_prep_fused_kernel(
    EdgeIdx S, EdgeIdx D, int* __restrict__ bincursor, unsigned* __restrict__ binbuf,
    PrepArgs P)
{
    __shared__ unsigned stage[ECHUNK];
    __shared__ int hist4[4][NBIN];
    __shared__ int hist[NBIN], off[NBIN], cur[NBIN], gbase[NBIN];
    int bid = blockIdx.x, tid = threadIdx.x;
    if (bid < SCAT_BLKS) {
        // ---------------- bin_scatter ----------------
        int g = bid / NCHUNK, chunk = bid - g * NCHUNK;
        const int* src = S.p[g];
        const int* dst = D.p[g];
        int lane = tid & 63, w = tid >> 6;
        for (int b = tid; b < 4 * NBIN; b += 256) (&hist4[0][0])[b] = 0;
        __syncthreads();
        int base = chunk * ECHUNK;
        int s[ECHUNK / 256], d[ECHUNK / 256];
#pragma unroll
        for (int k = 0; k < ECHUNK / 256; ++k) {
            int i = base + k * 256 + tid;
            if (i < E_EDGES) {
                s[k] = src[i];
                d[k] = dst[i];
                atomicAdd(&hist4[w][s[k] >> BIN_SHIFT], 1);
            } else s[k] = -1;
        }
        __syncthreads();
        if (w == 0) {
            int i1 = 64 + lane;
            int v0 = 0, v1 = 0;
            if (lane < NBIN) v0 = hist4[0][lane] + hist4[1][lane] + hist4[2][lane] + hist4[3][lane];
            if (i1 < NBIN) v1 = hist4[0][i1] + hist4[1][i1] + hist4[2][i1] + hist4[3][i1];
            int x0 = v0, x1 = v1;
#pragma unroll
            for (int o = 1; o < 64; o <<= 1) {
                int t0 = __shfl_up(x0, o, 64);
                int t1 = __shfl_up(x1, o, 64);
                if (lane >= o) { x0 += t0; x1 += t1; }
            }
            int tot0 = __shfl(x0, 63, 64);
            if (lane < NBIN) { hist[lane] = v0; off[lane] = x0 - v0; cur[lane] = x0 - v0; }
            if (i1 < NBIN) { hist[i1] = v1; off[i1] = tot0 + x1 - v1; cur[i1] = tot0 + x1 - v1; }
        }
        __syncthreads();
        if (tid < NBIN) gbase[tid] = hist[tid] ? atomicAdd(&bincursor[g * NBIN + tid], hist[tid]) : 0;
        __syncthreads();
#pragma unroll
        for (int k = 0; k < ECHUNK / 256; ++k) {
            if (s[k] >= 0) {
                int bin = s[k] >> BIN_SHIFT;
                int pos = atomicAdd(&cur[bin], 1);
                stage[pos] = ((unsigned)(s[k] & 511) << 10) | (unsigned)d[k];
            }
        }
        __syncthreads();
        size_t gslot = (size_t)g * NBIN * BINCAP;
        for (int b = w; b < NBIN; b += 4) {
            int len = hist[b];
            if (!len) continue;
            int gb = gbase[b];
            int avail = BINCAP - gb;
            if (avail <= 0) continue;
            if (len > avail) len = avail;
            int lo = off[b];
            size_t obase = gslot + (size_t)b * BINCAP + gb;
            for (int j = lane; j < len; j += 64)
                binbuf[obase + j] = stage[lo + j];
        }
        return;
    }
    // ---------------- prep (reuses `stage` LDS as float scratch) ----------------
    float* sh = (float*)stage;
    int pb = bid - SCAT_BLKS;
    if (pb < 256) {
        // W_R column c: bkv_c -> M2 = w2w@bkv_c -> W_R[:,c] = w1w@M2 (*SL2E); bR_c
        int c = pb;
        const bf16 z = __float2bfloat16(0.f);
        if (c >= R_STRIDE) {
            if (tid < KP_HE) { P.WRt_hi[c * KP_HE + tid] = z; P.WRt_lo[c * KP_HE + tid] = z; }
            return;
        }
        float* bkv = sh;          // [128]
        float* M2 = sh + 128;     // [512]
        float* psum = sh + 640;   // [32]
        int g = c / 72, j = c - g * 72;
        if (tid < 128) {
            float v = 0.f;
            if (j < 64) v = P.w6[g][j * E_DIM + tid];
            else if (j == 64) v = P.b6[g][tid];
            bkv[tid] = v;
        }
        __syncthreads();
        for (int h = tid; h < HE_DIM; h += 256) {
            const float* w2row = P.w2w + (size_t)h * E_DIM;
            float s = 0.f;
#pragma unroll 4
            for (int k = 0; k < 128; ++k) s = fmaf(w2row[k], bkv[k], s);
            M2[h] = s;
        }
        __syncthreads();
        if (tid < IN_F) {
            const float* w1row = P.w1w + (size_t)tid * HE_DIM;
            float s = 0.f;
#pragma unroll 4
            for (int h = 0; h < HE_DIM; ++h) s = fmaf(w1row[h], M2[h], s);
            bf16 hh, ll; split2(s * SL2E, hh, ll);
            P.WRt_hi[c * KP_HE + tid] = hh;
            P.WRt_lo[c * KP_HE + tid] = ll;
        } else if (tid < KP_HE) {
            P.WRt_hi[c * KP_HE + tid] = z;
            P.WRt_lo[c * KP_HE + tid] = z;
        } else {
            int l = tid - 224; // 0..31
            float s = 0.f;
#pragma unroll 4
            for (int h = l * 16; h < l * 16 + 16; ++h) s = fmaf(P.w1b[h], M2[h], s);
#pragma unroll
            for (int k = l * 4; k < l * 4 + 4; ++k) s = fmaf(P.w2b[k], bkv[k], s);
            psum[l] = s;
        }
        __syncthreads();
        if (tid == 224) {
            float s = 0.f;
#pragma unroll
            for (int l = 0; l < 32; ++l) s += psum[l];
            P.bR[c] = s * SL2E;
        }
    } else if (pb < 449) {
        // Wct^T hi/lo [256][192]; row 192 -> b_comp
        int row = pb - 256;
        int n = tid;
        if (row < 192) {
            int g = row >> 6, i = row & 63;
            const float* w7 = P.w7[g];
            float s = 0.f;
#pragma unroll 4
            for (int k = 0; k < 128; ++k)
                s = fmaf(w7[i * 128 + k], P.mlp1w[(size_t)(g * 128 + k) * 256 + n], s);
            bf16 h, l; split2(s, h, l);
            P.Wct_hi[n * T_STRIDE + row] = h;
            P.Wct_lo[n * T_STRIDE + row] = l;
        } else {
            float s = P.mlp1b[n];
            for (int g = 0; g < 3; ++g)
#pragma unroll 4
                for (int k = 0; k < 128; ++k)
                    s = fmaf(P.b7[g][k], P.mlp1w[(size_t)(g * 128 + k) * 256 + n], s);
            P.b_comp[n] = s;
        }
    } else if (pb < 577) {
        // mlp2w^T hi/lo [128][256]
        int n = pb - 449;
        int k = tid;
        float v = P.mlp2w[(size_t)k * 128 + n];
        bf16 h, l; split2(v, h, l);
        P.Wm2t_hi[n * 256 + k] = h;
        P.Wm2t_lo[n * 256 + k] = l;
    } else {
        // node q projection: one block per node row
        int b = pb - 577; // 0..1488
        int g = (b < 167) ? 0 : (b < 1048 ? 1 : 2);
        int row = b - (g == 0 ? 0 : (g == 1 ? 167 : 1048));
        int Dt = (g == 0) ? 167 : (g == 1 ? 881 : 441);
        const float* feat = P.feat[g] + (size_t)row * Dt;
        const float* w5 = P.w5[g];
        int col = tid & 63, ks = tid >> 6;
        float s = 0.f;
#pragma unroll 4
        for (int k = ks; k < Dt; k += 4)
            s = fmaf(feat[k], w5[k * Q_DIM + col], s);
        sh[ks * 64 + col] = s;
        __syncthreads();
        if (ks == 0)
            P.q_t[(size_t)b * Q_DIM + col] =
                sh[col] + sh[64 + col] + sh[128 + col] + sh[192 + col] + P.b5[g][col];
    }
}

// ---------------- f32-A split-3-pass MFMA GEMM body (reg prefetch, LDS-staged A+B, LDS-transpose epilogue) ----------------
__device__ __forceinline__ void gemm_f32A_body(
    char* smem, int bx, int by, int tid,
    const float* __restrict__ A, int lda, int Kp, int Mvalid,
    const bf16* __restrict__ Bthg, const bf16* __restrict__ Btlg,
    const float* __restrict__ bias,
    float* __restrict__ C, int M, int N, int ldc)
{
    bf16* Ah = (bf16*)smem;
    bf16* Al = Ah + 128 * LDSD;
    bf16* Bh = Al + 128 * LDSD;
    bf16* Bl = Bh + 64 * LDSD;
    const int bm = bx * 128, bn = by * 64;
    const int lane = tid & 63, w = tid >> 6;
    const int kgrp = lane >> 4, lr = lane & 15;
    const int arow = tid >> 1, ahalf = (tid & 1) * 16;
    const int brow = tid >> 2, bq = (tid & 3) * 8;
    f32x4 acc[2][4] = {};

    float va[16];
    uint4 vb0, vb1;
    const int arowg = bm + arow;

    // prologue loads (k0 = 0)
    {
        int kb = ahalf;
        if (arowg < Mvalid && kb + 16 <= lda) {
            const float* ap = A + (size_t)arowg * lda + kb;
            *(float4*)&va[0]  = *(const float4*)ap;
            *(float4*)&va[4]  = *(const float4*)(ap + 4);
            *(float4*)&va[8]  = *(const float4*)(ap + 8);
            *(float4*)&va[12] = *(const float4*)(ap + 12);
        } else {
#pragma unroll
            for (int j = 0; j < 16; ++j) {
                int k = kb + j;
                va[j] = (arowg < Mvalid && k < lda) ? A[(size_t)arowg * lda + k] : 0.f;
            }
        }
        const size_t bbase = (size_t)(bn + brow) * Kp + bq;
        vb0 = *(const uint4*)(Bthg + bbase);
        vb1 = *(const uint4*)(Btlg + bbase);
    }

    for (int k0 = 0; k0 < Kp; k0 += 32) {
        {
            u16x8 H0, H1, L0, L1;
#pragma unroll
            for (int j = 0; j < 8; ++j) {
                unsigned short h, l;
                split2u(va[j], h, l);       H0[j] = h; L0[j] = l;
                split2u(va[8 + j], h, l);   H1[j] = h; L1[j] = l;
            }
            *(u16x8*)&Ah[arow * LDSD + ahalf] = H0;
            *(u16x8*)&Ah[arow * LDSD + ahalf + 8] = H1;
            *(u16x8*)&Al[arow * LDSD + ahalf] = L0;
            *(u16x8*)&Al[arow * LDSD + ahalf + 8] = L1;
            *(uint4*)&Bh[brow * LDSD + bq] = vb0;
            *(uint4*)&Bl[brow * LDSD + bq] = vb1;
        }
        if (k0 + 32 < Kp) {
            int kb = k0 + 32 + ahalf;
            if (arowg < Mvalid && kb + 16 <= lda) {
                const float* ap = A + (size_t)arowg * lda + kb;
                *(float4*)&va[0]  = *(const float4*)ap;
                *(float4*)&va[4]  = *(const float4*)(ap + 4);
                *(float4*)&va[8]  = *(const float4*)(ap + 8);
                *(float4*)&va[12] = *(const float4*)(ap + 12);
            } else {
#pragma unroll
                for (int j = 0; j < 16; ++j) {
                    int k = kb + j;
                    va[j] = (arowg < Mvalid && k < lda) ? A[(size_t)arowg * lda + k] : 0.f;
                }
            }
            const size_t bbase = (size_t)(bn + brow) * Kp + k0 + 32 + bq;
            vb0 = *(const uint4*)(Bthg + bbase);
            vb1 = *(const uint4*)(Btlg + bbase);
        }
        __syncthreads();
        bf16x8s afh[2], afl[2], bfh[4], bfl[4];
#pragma unroll
        for (int mi = 0; mi < 2; ++mi) {
            int r = w * 32 + mi * 16 + lr;
            afh[mi] = *(const bf16x8s*)&Ah[r * LDSD + kgrp * 8];
            afl[mi] = *(const bf16x8s*)&Al[r * LDSD + kgrp * 8];
        }
#pragma unroll
        for (int ni = 0; ni < 4; ++ni) {
            int r = ni * 16 + lr;
            bfh[ni] = *(const bf16x8s*)&Bh[r * LDSD + kgrp * 8];
            bfl[ni] = *(const bf16x8s*)&Bl[r * LDSD + kgrp * 8];
        }
#pragma unroll
        for (int mi = 0; mi < 2; ++mi)
#pragma unroll
            for (int ni = 0; ni < 4; ++ni) {
                acc[mi][ni] = __builtin_amdgcn_mfma_f32_16x16x32_bf16(afh[mi], bfh[ni], acc[mi][ni], 0, 0, 0);
                acc[mi][ni] = __builtin_amdgcn_mfma_f32_16x16x32_bf16(afl[mi], bfh[ni], acc[mi][ni], 0, 0, 0);
                acc[mi][ni] = __builtin_amdgcn_mfma_f32_16x16x32_bf16(afh[mi], bfl[ni], acc[mi][ni], 0, 0, 0);
            }
        __syncthreads();
    }

    // LDS-transpose epilogue: full-line float4 stores (per-wave 4KB region)
    float* ep = (float*)(smem + w * 4096);
    float bv[4];
#pragma unroll
    for (int ni = 0; ni < 4; ++ni) {
        int col = bn + ni * 16 + lr;
        bv[ni] = (col < N) ? bias[col] : 0.f;
    }
    __syncthreads();
#pragma unroll
    for (int mi = 0; mi < 2; ++mi) {
#pragma unroll
        for (int ni = 0; ni < 4; ++ni)
#pragma unroll
            for (int r = 0; r < 4; ++r)
                ep[(kgrp * 4 + r) * 64 + ni * 16 + lr] = acc[mi][ni][r] + bv[ni];
#pragma unroll
        for (int s = 0; s < 4; ++s) {
            int row = s * 4 + (lane >> 4);
            int colv = lane & 15;
            int row_g = bm + w * 32 + mi * 16 + row;
            int col_g = bn + colv * 4;
            if (row_g < M && col_g + 4 <= N) {
                float4 v = *(const float4*)&ep[row * 64 + colv * 4];
                *(float4*)&C[(size_t)row_g * ldc + col_g] = v;
            }
        }
        if (mi == 0) __syncthreads();
    }
}

// ---------------- fused: bin_csr (294 blocks) + R-gemm (1564 blocks, XCD-swizzled) ----------------
__global__ __launch_bounds__(256) void csr_gemm_fused_kernel(
    const unsigned* __restrict__ binbuf, const int* __restrict__ bincursor,
    int2* __restrict__ rows2_all, int* __restrict__ ebuf,
    const float* __restrict__ he_feat,
    const bf16* __restrict__ WRt_hi, const bf16* __restrict__ WRt_lo,
    const float* __restrict__ bR, float* __restrict__ R)
{
    __shared__ __attribute__((aligned(16))) char smem[30720];
    int bid = blockIdx.x, tid = threadIdx.x;
    if (bid < 3 * NBIN) {
        int* hist = (int*)smem;
        int* cur = hist + 512;
        int* cs = cur + 512;
        int g = bid / NBIN, b = bid - g * NBIN;
        int cnt = min(bincursor[g * NBIN + b], BINCAP);
        size_t sbase = ((size_t)g * NBIN + b) * BINCAP;
        int h0 = b << BIN_SHIFT;
        int hN = min(512, N_HE - h0);
        int ebase_rel = b * BINCAP;
        int2* rows2 = rows2_all + g * N_HE;
        int lane = tid & 63, w = tid >> 6;
        hist[tid] = 0; hist[tid + 256] = 0;
        __syncthreads();
        for (int i = tid; i < cnt; i += 256)
            atomicAdd(&hist[binbuf[sbase + i] >> 10], 1);
        __syncthreads();
#pragma unroll
        for (int c2 = 0; c2 < 2; ++c2) {
            int c = w * 2 + c2, idx = c * 64 + lane;
            int v = hist[idx], x = v;
#pragma unroll
            for (int o = 1; o < 64; o <<= 1) {
                int t = __shfl_up(x, o, 64);
                if (lane >= o) x += t;
            }
            cur[idx] = x - v;
            if (lane == 63) cs[c] = x;
        }
        __syncthreads();
        if (tid == 0) {
            int run = 0;
#pragma unroll
            for (int c = 0; c < 8; ++c) { int t = cs[c]; cs[c] = run; run += t; }
        }
        __syncthreads();
#pragma unroll
        for (int c2 = 0; c2 < 2; ++c2) {
            int c = w * 2 + c2, idx = c * 64 + lane;
            int e = cur[idx] + cs[c];
            cur[idx] = e;
            if (idx < hN) rows2[h0 + idx] = make_int2(ebase_rel + e, ebase_rel + e + hist[idx]);
        }
        __syncthreads();
        for (int i = tid; i < cnt; i += 256) {
            unsigned p = binbuf[sbase + i];
            int pos = atomicAdd(&cur[p >> 10], 1);
            ebuf[sbase + pos] = (int)((p & 1023u) << 8); // byte offset into q_t rows (256 B/row)
        }
    } else {
        int q = bid - 3 * NBIN;
        int bx, by;
        xcd_swizzle(q, MB * 4, 4, bx, by);
        gemm_f32A_body(smem, bx, by, tid,
                       he_feat, IN_F, KP_HE, N_HE, WRt_hi, WRt_lo, bR,
                       R, N_HE, R_STRIDE, R_LD);
    }
}

// ---------------- bf16-A 2-pass MFMA GEMM, XCD swizzle, reg prefetch, LDS-transpose epilogue ----------------
template <bool OUT_BF16, bool MASK_ROW>
__global__ __launch_bounds__(256) void mfma_gemm_bf16A_kernel(
    int nby,
    const bf16* __restrict__ A, int lda, int Kp,
    const bf16* __restrict__ Bthg, const bf16* __restrict__ Btlg,
    const float* __restrict__ bias,
    float* __restrict__ Cf, bf16* __restrict__ Cb,
    int M, int N, int ldc)
{
    __shared__ __attribute__((aligned(16))) char smemB[20480];
    bf16* Ah = (bf16*)smemB;
    bf16* Bh = Ah + 128 * LDSD;
    bf16* Bl = Bh + 64 * LDSD;
    const int tid = threadIdx.x;
    int bx, by;
    xcd_swizzle(blockIdx.x, gridDim.x, nby, bx, by);
    const int bm = bx * 128, bn = by * 64;
    const int lane = tid & 63, w = tid >> 6;
    const int kgrp = lane >> 4, lr = lane & 15;
    const int arow = tid >> 1, ahalf = (tid & 1) * 16;
    const int brow = tid >> 2, bq = (tid & 3) * 8;
    f32x4 acc[2][4] = {};

    uint4 ra0, ra1, rb0, rb1;
    {
        const bf16* ap = A + (size_t)(bm + arow) * lda + ahalf;
        ra0 = *(const uint4*)ap;
        ra1 = *(const uint4*)(ap + 8);
        const size_t bbase = (size_t)(bn + brow) * Kp + bq;
        rb0 = *(const uint4*)(Bthg + bbase);
        rb1 = *(const uint4*)(Btlg + bbase);
    }

    for (int k0 = 0; k0 < Kp; k0 += 32) {
        *(uint4*)&Ah[arow * LDSD + ahalf] = ra0;
        *(uint4*)&Ah[arow * LDSD + ahalf + 8] = ra1;
        *(uint4*)&Bh[brow * LDSD + bq] = rb0;
        *(uint4*)&Bl[brow * LDSD + bq] = rb1;
        if (k0 + 32 < Kp) {
            const bf16* ap = A + (size_t)(bm + arow) * lda + k0 + 32 + ahalf;
            ra0 = *(const uint4*)ap;
            ra1 = *(const uint4*)(ap + 8);
            const size_t bbase = (size_t)(bn + brow) * Kp + k0 + 32 + bq;
            rb0 = *(const uint4*)(Bthg + bbase);
            rb1 = *(const uint4*)(Btlg + bbase);
        }
        __syncthreads();
        bf16x8s afh[2], bfh[4], bfl[4];
#pragma unroll
        for (int mi = 0; mi < 2; ++mi) {
            int r = w * 32 + mi * 16 + lr;
            afh[mi] = *(const bf16x8s*)&Ah[r * LDSD + kgrp * 8];
        }
#pragma unroll
        for (int ni = 0; ni < 4; ++ni) {
            int r = ni * 16 + lr;
            bfh[ni] = *(const bf16x8s*)&Bh[r * LDSD + kgrp * 8];
            bfl[ni] = *(const bf16x8s*)&Bl[r * LDSD + kgrp * 8];
        }
#pragma unroll
        for (int mi = 0; mi < 2; ++mi)
#pragma unroll
            for (int ni = 0; ni < 4; ++ni) {
                acc[mi][ni] = __builtin_amdgcn_mfma_f32_16x16x32_bf16(afh[mi], bfh[ni], acc[mi][ni], 0, 0, 0);
                acc[mi][ni] = __builtin_amdgcn_mfma_f32_16x16x32_bf16(afh[mi], bfl[ni], acc[mi][ni], 0, 0, 0);
            }
        __syncthreads();
    }

    // LDS-transpose epilogue (per-wave 4KB region)
    float bv[4];
#pragma unroll
    for (int ni = 0; ni < 4; ++ni) {
        int col = bn + ni * 16 + lr;
        bv[ni] = (col < N) ? bias[col] : 0.f;
    }
    __syncthreads();
    if (OUT_BF16) {
        unsigned short* ep = (unsigned short*)(smemB + w * 4096);
#pragma unroll
        for (int mi = 0; mi < 2; ++mi) {
#pragma unroll
            for (int ni = 0; ni < 4; ++ni)
#pragma unroll
                for (int r = 0; r < 4; ++r)
                    ep[(kgrp * 4 + r) * 64 + ni * 16 + lr] = bf16bits(fmaxf(acc[mi][ni][r] + bv[ni], 0.f));
#pragma unroll
            for (int s = 0; s < 2; ++s) {
                int row = s * 8 + (lane >> 3);
                int col8 = lane & 7;
                int row_g = bm + w * 32 + mi * 16 + row;
                uint4 v = *(const uint4*)&ep[row * 64 + col8 * 8];
                *(uint4*)&Cb[(size_t)row_g * ldc + bn + col8 * 8] = v;
            }
            if (mi == 0) __syncthreads();
        }
    } else {
        float* ep = (float*)(smemB + w * 4096);
#pragma unroll
        for (int mi = 0; mi < 2; ++mi) {
#pragma unroll
            for (int ni = 0; ni < 4; ++ni)
#pragma unroll
                for (int r = 0; r < 4; ++r)
                    ep[(kgrp * 4 + r) * 64 + ni * 16 + lr] = fmaxf(acc[mi][ni][r] + bv[ni], 0.f);
#pragma unroll
            for (int s = 0; s < 4; ++s) {
                int row = s * 4 + (lane >> 4);
                int colv = lane & 15;
                int row_g = bm + w * 32 + mi * 16 + row;
                int col_g = bn + colv * 4;
                if ((!MASK_ROW || row_g < M) && col_g + 4 <= N) {
                    float4 v = *(const float4*)&ep[row * 64 + colv * 4];
                    *(float4*)&Cf[(size_t)row_g * ldc + col_g] = v;
                }
            }
            if (mi == 0) __syncthreads();
        }
    }
}

// ---------------- attention: fixed-max, log2-domain, DPP reduce, bf16 T out ----------------
__global__ __launch_bounds__(256) void attn_kernel(
    const float* __restrict__ R,        // [N_HE][R_LD], scores pre-scaled by SL2E
    const float* __restrict__ q_t,      // [1489][64]
    const int2* __restrict__ rows2_all, // [3][N_HE] group-relative (start,end)
    const int* __restrict__ ebuf_all,   // [3][NBIN*BINCAP], holds d<<8 byte offsets
    bf16* __restrict__ T)               // [M_PAD][192] bf16
{
    int wid = blockIdx.x * 4 + (threadIdx.x >> 6);
    int lane = threadIdx.x & 63;
    int g = wid / N_HE;
    int h = wid - g * N_HE;
    const int toff_tab[3] = {0, 167, 1048};
    const char* qb = (const char*)(q_t + (size_t)toff_tab[g] * Q_DIM);
    const int* ebuf = ebuf_all + (size_t)g * NBIN * BINCAP;
    int2 se = rows2_all[g * N_HE + h];
    int start = se.x, end = se.y;

    int sub = lane >> 4, sl = lane & 15;
    const float* Rrow = R + (size_t)h * R_LD + g * 72;
    float4 r4 = *reinterpret_cast<const float4*>(Rrow + sl * 4);
    float ch = Rrow[64];
    int slo = sl * 16;

    float denom = 0.f;
    float acc0 = 0.f, acc1 = 0.f, acc2 = 0.f, acc3 = 0.f;

    for (int i0 = start + sub * 2; i0 < end; i0 += 8) {
        bool ok1 = (i0 + 1) < end;
        int o0 = ebuf[i0];
        int o1 = ebuf[ok1 ? i0 + 1 : i0];
        float4 t0 = *reinterpret_cast<const float4*>(qb + o0 + slo);
        float4 t1 = *reinterpret_cast<const float4*>(qb + o1 + slo);
        float p0 = t0.x * r4.x;
        p0 = fmaf(t0.y, r4.y, p0); p0 = fmaf(t0.z, r4.z, p0); p0 = fmaf(t0.w, r4.w, p0);
        float p1 = t1.x * r4.x;
        p1 = fmaf(t1.y, r4.y, p1); p1 = fmaf(t1.z, r4.z, p1); p1 = fmaf(t1.w, r4.w, p1);
        p0 = red16(p0);
        p1 = red16(p1);
        float s0 = p0 + ch; s0 = fmaxf(s0, 0.01f * s0);   // leaky_relu (pre-scaled)
        float s1 = p1 + ch; s1 = fmaxf(s1, 0.01f * s1);
        float w0 = exp2_fast(s0);
        float w1 = ok1 ? exp2_fast(s1) : 0.f;
        denom += w0 + w1;
        acc0 = fmaf(w0, t0.x, fmaf(w1, t1.x, acc0));
        acc1 = fmaf(w0, t0.y, fmaf(w1, t1.y, acc1));
        acc2 = fmaf(w0, t0.z, fmaf(w1, t1.z, acc2));
        acc3 = fmaf(w0, t0.w, fmaf(w1, t1.w, acc3));
    }

    // cross-subgroup LANE-WISE sums (lane i <-> i^16, i^32)
    denom += __shfl_xor(denom, 16, 64); denom += __shfl_xor(denom, 32, 64);
    acc0 += __shfl_xor(acc0, 16, 64); acc0 += __shfl_xor(acc0, 32, 64);
    acc1 += __shfl_xor(acc1, 16, 64); acc1 += __shfl_xor(acc1, 32, 64);
    acc2 += __shfl_xor(acc2, 16, 64); acc2 += __shfl_xor(acc2, 32, 64);
    acc3 += __shfl_xor(acc3, 16, 64); acc3 += __shfl_xor(acc3, 32, 64);
    if (sub == 0) {
        float rden = 1.f / fmaxf(denom, 1e-20f);
        ushort4 o;
        o.x = bf16bits(acc0 * rden);
        o.y = bf16bits(acc1 * rden);
        o.z = bf16bits(acc2 * rden);
        o.w = bf16bits(acc3 * rden);
        *reinterpret_cast<ushort4*>(T + (size_t)h * T_STRIDE + g * 64 + sl * 4) = o;
    }
}

// ---------------- launch ----------------
extern "C" void kernel_launch(void* const* d_in, const int* in_sizes, int n_in,
                              void* d_out, int out_size, void* d_ws, size_t ws_size,
                              hipStream_t stream)
{
    const float* he_feat = (const float*)d_in[0];
    float* out = (float*)d_out;

    EdgeIdx Esrc, Edst;
    for (int g = 0; g < 3; ++g) {
        Esrc.p[g] = (const int*)d_in[34 + 2 * g];
        Edst.p[g] = (const int*)d_in[35 + 2 * g];
    }

    char* base = (char*)d_ws;
    size_t off = 0;
    auto alloc = [&](size_t bytes) -> void* {
        void* r = (void*)(base + off);
        off = (off + bytes + 255) & ~(size_t)255;
        return r;
    };
    // ---- persistent small region (~1.5 MB) ----
    bf16* WRt_hi = (bf16*)alloc(256 * KP_HE * 2);
    bf16* WRt_lo = (bf16*)alloc(256 * KP_HE * 2);
    float* bR = (float*)alloc(R_STRIDE * 4);
    bf16* Wct_hi = (bf16*)alloc(256 * T_STRIDE * 2);
    bf16* Wct_lo = (bf16*)alloc(256 * T_STRIDE * 2);
    float* b_comp = (float*)alloc(256 * 4);
    bf16* Wm2t_hi = (bf16*)alloc(128 * 256 * 2);
    bf16* Wm2t_lo = (bf16*)alloc(128 * 256 * 2);
    float* q_t = (float*)alloc(N_NODES * Q_DIM * 4);
    int* bincursor = (int*)alloc(3 * NBIN * 4);
    int2* rows2 = (int2*)alloc((size_t)3 * N_HE * 8);
    // ---- big buffers with lifetime overlays (~82 MB total) ----
    size_t T_start = off;
    bf16* T = (bf16*)alloc((size_t)M_PAD * T_STRIDE * 2);      // 19.2 MB [attn -> mlp1]
    size_t R_start = off;
    float* R = (float*)alloc((size_t)N_HE * R_LD * 4);         // 44.8 MB [R-gemm -> attn]
    int* ebuf = (int*)alloc((size_t)3 * NBIN * BINCAP * 4);    // 15.4 MB [csr -> attn]
    // overlays:
    unsigned* binbuf = (unsigned*)(base + T_start);             // 15.4 MB [scatter -> csr]
    bf16* h1 = (bf16*)(base + R_start);                         // 25.6 MB [mlp1 -> mlp2], over dead R

    hipMemsetAsync(bincursor, 0, 3 * NBIN * 4, stream);

    // ---- fused scatter + prep ----
    PrepArgs P;
    P.w1w = (const float*)d_in[4]; P.w1b = (const float*)d_in[5];
    P.w2w = (const float*)d_in[6]; P.w2b = (const float*)d_in[7];
    for (int g = 0; g < 3; ++g) {
        P.w6[g] = (const float*)d_in[18 + 4 * g];
        P.b6[g] = (const float*)d_in[19 + 4 * g];
        P.w7[g] = (const float*)d_in[20 + 4 * g];
        P.b7[g] = (const float*)d_in[21 + 4 * g];
        P.feat[g] = (const float*)d_in[1 + g];
        P.w5[g] = (const float*)d_in[12 + 2 * g];
        P.b5[g] = (const float*)d_in[13 + 2 * g];
    }
    P.WRt_hi = WRt_hi; P.WRt_lo = WRt_lo; P.bR = bR;
    P.mlp1w = (const float*)d_in[30]; P.mlp1b = (const float*)d_in[31];
    P.Wct_hi = Wct_hi; P.Wct_lo = Wct_lo; P.b_comp = b_comp;
    P.mlp2w = (const float*)d_in[32];
    P.Wm2t_hi = Wm2t_hi; P.Wm2t_lo = Wm2t_lo;
    P.q_t = q_t;
    scatter_prep_fused_kernel<<<SCAT_BLKS + PREP_BLKS, 256, 0, stream>>>(
        Esrc, Edst, bincursor, binbuf, P);

    // ---- fused CSR finalize + R-gemm (XCD-swizzled) ----
    csr_gemm_fused_kernel<<<3 * NBIN + MB * 4, 256, 0, stream>>>(
        binbuf, bincursor, rows2, ebuf, he_feat, WRt_hi, WRt_lo, bR, R);

    // ---- attention -> T bf16 (overwrites binbuf: dead) ----
    attn_kernel<<<(3 * N_HE) / 4, 256, 0, stream>>>(R, q_t, rows2, ebuf, T);

    const float* mlp2b = (const float*)d_in[33];
    // h1 = relu(T @ W_comp + b_comp) -> bf16 [M_PAD][256]  (overwrites R: dead)
    mfma_gemm_bf16A_kernel<true, false><<<MB * 4, 256, 0, stream>>>(
        4, T, T_STRIDE, T_STRIDE, Wct_hi, Wct_lo, b_comp, nullptr, h1, M_PAD, 256, 256);
    // out = relu(h1 @ mlp2w + mlp2b) -> f32 [N_HE][128]
    mfma_gemm_bf16A_kernel<false, true><<<MB * 2, 256, 0, stream>>>(
        2, h1, 256, 256, Wm2t_hi, Wm2t_lo, mlp2b, out, nullptr, N_HE, E_DIM, E_DIM);
}